// Round 3
// baseline (242.506 us; speedup 1.0000x reference)
//
#include <hip/hip_runtime.h>
#include <hip/hip_bf16.h>

typedef __attribute__((ext_vector_type(8))) short short8;
typedef __attribute__((ext_vector_type(4))) short short4v;
typedef __attribute__((ext_vector_type(4))) float floatx4;

constexpr int B = 4, L = 2048, H = 16, E = 64, D = 1024;
constexpr int STR = 72;   // prep LDS transpose stride (144 B rows, 16B-aligned)
constexpr float SCL_LOG2E = 0.125f * 1.4426950408889634f;  // 1/sqrt(64) * log2(e)

__device__ __forceinline__ short bf16_bits(float x) {
    __hip_bfloat16 b = __float2bfloat16(x);
    return *(const short*)&b;
}

__device__ __forceinline__ short8 packq8(float4 a, float4 c, float scl) {
    short8 r;
    r[0] = bf16_bits(a.x * scl); r[1] = bf16_bits(a.y * scl);
    r[2] = bf16_bits(a.z * scl); r[3] = bf16_bits(a.w * scl);
    r[4] = bf16_bits(c.x * scl); r[5] = bf16_bits(c.y * scl);
    r[6] = bf16_bits(c.z * scl); r[7] = bf16_bits(c.w * scl);
    return r;
}

// Direct global->LDS DMA, 16B/lane. LDS dest = wave-uniform base + lane*16.
__device__ __forceinline__ void load_lds16(const short* g, short* l) {
    __builtin_amdgcn_global_load_lds(
        (const __attribute__((address_space(1))) unsigned int*)g,
        (__attribute__((address_space(3))) unsigned int*)l, 16, 0, 0);
}

// ---------------------------------------------------------------------------
// Prep: emit K and V^T per 64-s tile ALREADY IN MFMA-FRAGMENT ORDER so the
// main kernel's LDS staging and fragment reads are lane-linear (0 conflicts).
//
// K tile (8KB, 512x16B chunks): chunk f = (nt*2+h)*64 + quad*16 + c16
//   holds K[s = nt*16+c16][d = h*32 + quad*8 .. +8)
// V tile (8KB, 1024x8B chunks): chunk g = st*256 + dt*64 + qd*16 + c
//   holds V[s = st*16 + qd*4 .. +4)[d = dt*16 + c]   (i.e. V^T 4-s runs)
// ---------------------------------------------------------------------------
__global__ __launch_bounds__(256)
void prep_kv(const float* __restrict__ K, const float* __restrict__ V,
             short* __restrict__ Kb, short* __restrict__ Vt)
{
    __shared__ __align__(16) short vt[64 * STR];
    const int tid = threadIdx.x;
    const int bh = blockIdx.x >> 5, kt = blockIdx.x & 31;
    const int b = bh >> 4, h = bh & 15;

    const float* Kp = K + ((size_t)(b * L + kt * 64)) * D + h * E;
    const float* Vp = V + ((size_t)(b * L + kt * 64)) * D + h * E;
    short* Kop = Kb + ((size_t)(bh * 32 + kt)) * 4096;
    short* Vop = Vt + ((size_t)(bh * 32 + kt)) * 4096;

    // ---- K: global fp32 -> bf16, fragment-ordered 16B chunks ----
    #pragma unroll
    for (int it = 0; it < 2; ++it) {
        int f = it * 256 + tid;
        int nt = f >> 7, hh = (f >> 6) & 1, qd = (f >> 4) & 3, cc = f & 15;
        int s = nt * 16 + cc, d0 = hh * 32 + qd * 8;
        const float* p = Kp + (size_t)s * D + d0;
        float4 x = *(const float4*)p;
        float4 y = *(const float4*)(p + 4);
        union { short sh[8]; uint4 u; } pk;
        pk.sh[0] = bf16_bits(x.x); pk.sh[1] = bf16_bits(x.y);
        pk.sh[2] = bf16_bits(x.z); pk.sh[3] = bf16_bits(x.w);
        pk.sh[4] = bf16_bits(y.x); pk.sh[5] = bf16_bits(y.y);
        pk.sh[6] = bf16_bits(y.z); pk.sh[7] = bf16_bits(y.w);
        *(uint4*)(Kop + (size_t)f * 8) = pk.u;
    }

    // ---- V phase 1: transpose into LDS vt[d][s] ----
    #pragma unroll
    for (int p = 0; p < 4; ++p) {
        int idx = p * 256 + tid;
        int s = idx >> 4, c4 = (idx & 15) * 4;
        float4 g = *(const float4*)(Vp + (size_t)s * D + c4);
        vt[(c4 + 0) * STR + s] = bf16_bits(g.x);
        vt[(c4 + 1) * STR + s] = bf16_bits(g.y);
        vt[(c4 + 2) * STR + s] = bf16_bits(g.z);
        vt[(c4 + 3) * STR + s] = bf16_bits(g.w);
    }
    __syncthreads();

    // ---- V phase 2: fragment-ordered store (two 8B chunks -> one 16B) ----
    #pragma unroll
    for (int it = 0; it < 2; ++it) {
        int f16 = it * 256 + tid;
        int f8 = f16 * 2;                    // even -> pair shares (st,dt,quad)
        int st = f8 >> 8, dt = (f8 >> 6) & 3, qd = (f8 >> 4) & 3;
        int cA = f8 & 15;                    // even
        int dA = dt * 16 + cA, dB = dA + 1;
        int s0 = st * 16 + qd * 4;
        uint2 a = *(const uint2*)&vt[dA * STR + s0];
        uint2 c = *(const uint2*)&vt[dB * STR + s0];
        uint4 u; u.x = a.x; u.y = a.y; u.z = c.x; u.w = c.y;
        *(uint4*)(Vop + (size_t)f16 * 8) = u;
    }
}

// ---------------------------------------------------------------------------
// Single-fragment step (A only): cnt = #active 16-s chunks (4 if interior),
// diag => mask applies exactly at chunk nt == cnt-1.
// Lane holds S^T[s = s_base + nt*16 + r][m = mrow(lane)].
// ---------------------------------------------------------------------------
__device__ __forceinline__ void step_single(
    const short* __restrict__ kc, const short* __restrict__ vc,
    short8 qf0, short8 qf1, int mrow, int s_base, int cnt, bool diag,
    floatx4 (&o)[4], float& lsum, int lane)
{
    short4v pa[4];
    #pragma unroll
    for (int nt = 0; nt < 4; ++nt) {
        if (nt < cnt) {
            short8 kb0 = *(const short8*)&kc[nt * 1024 + lane * 8];
            short8 kb1 = *(const short8*)&kc[nt * 1024 + 512 + lane * 8];
            floatx4 acc = (floatx4){0.f, 0.f, 0.f, 0.f};
            acc = __builtin_amdgcn_mfma_f32_16x16x32_bf16(kb0, qf0, acc, 0, 0, 0);
            acc = __builtin_amdgcn_mfma_f32_16x16x32_bf16(kb1, qf1, acc, 0, 0, 0);
            if (diag && nt == cnt - 1) {
                const int s0 = s_base + nt * 16;
                #pragma unroll
                for (int r = 0; r < 4; ++r)
                    if (s0 + r > mrow) acc[r] = -__builtin_inff();
            }
            #pragma unroll
            for (int r = 0; r < 4; ++r) {
                float p = __builtin_amdgcn_exp2f(acc[r]);
                lsum += p;
                pa[nt][r] = bf16_bits(p);
            }
        }
    }
    #pragma unroll
    for (int st = 0; st < 4; ++st) {
        if (st < cnt) {
            #pragma unroll
            for (int dt = 0; dt < 4; ++dt) {
                short4v vb = *(const short4v*)&vc[(st * 4 + dt) * 256 + lane * 4];
                o[dt] = __builtin_amdgcn_mfma_f32_16x16x16bf16_1k(pa[st], vb, o[dt], 0, 0, 0);
            }
        }
    }
}

// ---------------------------------------------------------------------------
// Merged step: fragment A interior (always full), fragment B active with
// cntB chunks (diagB masks chunk cntB-1). K/V fragment reads are SHARED:
// one 16KB read set feeds 32 q-rows (2x arithmetic intensity per LDS byte).
// ---------------------------------------------------------------------------
__device__ __forceinline__ void step_merged(
    const short* __restrict__ kc, const short* __restrict__ vc,
    short8 qfA0, short8 qfA1, short8 qfB0, short8 qfB1,
    int mrowB, int s_base, int cntB, bool diagB,
    floatx4 (&oA)[4], floatx4 (&oB)[4], float& lA, float& lB, int lane)
{
    short4v paA[4], paB[4];
    #pragma unroll
    for (int nt = 0; nt < 4; ++nt) {
        short8 kb0 = *(const short8*)&kc[nt * 1024 + lane * 8];
        short8 kb1 = *(const short8*)&kc[nt * 1024 + 512 + lane * 8];
        floatx4 a = (floatx4){0.f, 0.f, 0.f, 0.f};
        a = __builtin_amdgcn_mfma_f32_16x16x32_bf16(kb0, qfA0, a, 0, 0, 0);
        a = __builtin_amdgcn_mfma_f32_16x16x32_bf16(kb1, qfA1, a, 0, 0, 0);
        #pragma unroll
        for (int r = 0; r < 4; ++r) {
            float p = __builtin_amdgcn_exp2f(a[r]);
            lA += p;
            paA[nt][r] = bf16_bits(p);
        }
        if (nt < cntB) {
            floatx4 bb = (floatx4){0.f, 0.f, 0.f, 0.f};
            bb = __builtin_amdgcn_mfma_f32_16x16x32_bf16(kb0, qfB0, bb, 0, 0, 0);
            bb = __builtin_amdgcn_mfma_f32_16x16x32_bf16(kb1, qfB1, bb, 0, 0, 0);
            if (diagB && nt == cntB - 1) {
                const int s0 = s_base + nt * 16;
                #pragma unroll
                for (int r = 0; r < 4; ++r)
                    if (s0 + r > mrowB) bb[r] = -__builtin_inff();
            }
            #pragma unroll
            for (int r = 0; r < 4; ++r) {
                float p = __builtin_amdgcn_exp2f(bb[r]);
                lB += p;
                paB[nt][r] = bf16_bits(p);
            }
        }
    }
    #pragma unroll
    for (int st = 0; st < 4; ++st) {
        #pragma unroll
        for (int dt = 0; dt < 4; ++dt) {
            short4v vb = *(const short4v*)&vc[(st * 4 + dt) * 256 + lane * 4];
            oA[dt] = __builtin_amdgcn_mfma_f32_16x16x16bf16_1k(paA[st], vb, oA[dt], 0, 0, 0);
            if (st < cntB)
                oB[dt] = __builtin_amdgcn_mfma_f32_16x16x16bf16_1k(paB[st], vb, oB[dt], 0, 0, 0);
        }
    }
}

__device__ __forceinline__ void store_frag(
    float lsum, const floatx4 (&o)[4], float* __restrict__ Op,
    int row_base, int c16, int quad)
{
    lsum += __shfl_xor(lsum, 16);
    lsum += __shfl_xor(lsum, 32);
    const int row0 = row_base + quad * 4;
    #pragma unroll
    for (int r = 0; r < 4; ++r) {
        const float inv = 1.f / __shfl(lsum, quad * 4 + r);  // l lives at lane c16==row
        #pragma unroll
        for (int dt = 0; dt < 4; ++dt)
            Op[(size_t)(row0 + r) * D + dt * 16 + c16] = o[dt][r] * inv;
    }
}

// ---------------------------------------------------------------------------
// Main: 1024 blocks x 256 threads (4 waves). Block = paired 64-row q-tiles
// (qtA=31-pp, qtB=pp); wave owns 16 rows of EACH. In the shared k-range one
// K/V fragment read set feeds both fragments (32 rows per 16KB LDS read =
// the LDS/MFMA balance point). 4 blocks/CU -> 4 independent barrier groups.
// With 64-row tiles: diag = exactly one tile per fragment, cnt = wave+1,
// and all branches are block-uniform.
// ---------------------------------------------------------------------------
__global__ __launch_bounds__(256, 4)
void attn_fwd_p(const float* __restrict__ Q, const short* __restrict__ Kb,
                const short* __restrict__ Vt, float* __restrict__ O)
{
    __shared__ __align__(16) short k_s[2 * 4096];   // 2 x 8KB K tiles
    __shared__ __align__(16) short v_s[2 * 4096];   // 2 x 8KB V tiles

    const int tid  = threadIdx.x;
    const int wave = tid >> 6;          // 0..3
    const int lane = tid & 63;
    const int c16  = lane & 15;
    const int quad = lane >> 4;

    // 1024 blocks = 64 bh x 16 pairs; all 16 pair-blocks of a head -> same XCD
    const int i  = (int)blockIdx.x;
    const int bh = ((i >> 7) << 3) | (i & 7);
    const int pp = (i >> 3) & 15;
    const int b  = bh >> 4;
    const int h  = bh & 15;

    const float* Qp  = Q  + ((size_t)b * L) * D + h * E;
    const short* Kbp = Kb + ((size_t)bh * 32) * 4096;
    const short* Vtp = Vt + ((size_t)bh * 32) * 4096;
    float*       Op  = O  + ((size_t)b * L) * D + h * E;

    const int qtA = 31 - pp, qtB = pp;     // 64-row q-tile indices, qtB < qtA
    const int nA  = qtA + 1;               // k-tiles (64-wide) for fragment A
    const int mA  = qtA * 64 + wave * 16;  // fragment A first q-row
    const int mB  = qtB * 64 + wave * 16;  // fragment B first q-row

    // ---- Q fragments straight from global fp32 (scale*log2e folded) ----
    const float* qra = Qp + (size_t)(mA + c16) * D + quad * 8;
    short8 qfA0 = packq8(*(const float4*)(qra),      *(const float4*)(qra + 4),  SCL_LOG2E);
    short8 qfA1 = packq8(*(const float4*)(qra + 32), *(const float4*)(qra + 36), SCL_LOG2E);
    const float* qrb = Qp + (size_t)(mB + c16) * D + quad * 8;
    short8 qfB0 = packq8(*(const float4*)(qrb),      *(const float4*)(qrb + 4),  SCL_LOG2E);
    short8 qfB1 = packq8(*(const float4*)(qrb + 32), *(const float4*)(qrb + 36), SCL_LOG2E);

    // ---- prologue: stage tile 0 into buffer 0 (direct-to-LDS) ----
    #pragma unroll
    for (int it = 0; it < 2; ++it) {
        int c = it * 256 + tid;
        load_lds16(Kbp + (size_t)c * 8, k_s + c * 8);
        load_lds16(Vtp + (size_t)c * 8, v_s + c * 8);
    }

    floatx4 oA[4], oB[4];
    #pragma unroll
    for (int dt = 0; dt < 4; ++dt) {
        oA[dt] = (floatx4){0.f, 0.f, 0.f, 0.f};
        oB[dt] = (floatx4){0.f, 0.f, 0.f, 0.f};
    }
    float lA = 0.f, lB = 0.f;

    for (int t = 0; t < nA; ++t) {
        __syncthreads();   // staging of t drained (vmcnt0) + reads of t-1 done
        const short* kc = k_s + (t & 1) * 4096;
        const short* vc = v_s + (t & 1) * 4096;

        if (t + 1 < nA) {  // stage t+1 into the other buffer (lands during compute)
            const size_t nb = (size_t)(t + 1) * 4096;
            short* kn = k_s + ((t + 1) & 1) * 4096;
            short* vn = v_s + ((t + 1) & 1) * 4096;
            #pragma unroll
            for (int it = 0; it < 2; ++it) {
                int c = it * 256 + tid;
                load_lds16(Kbp + nb + (size_t)c * 8, kn + c * 8);
                load_lds16(Vtp + nb + (size_t)c * 8, vn + c * 8);
            }
        }

        __builtin_amdgcn_s_setprio(1);
        const int sb = t * 64 + quad * 4;
        if (t < qtB) {
            step_merged(kc, vc, qfA0, qfA1, qfB0, qfB1, 0, sb, 4, false,
                        oA, oB, lA, lB, lane);
        } else if (t == qtB) {
            step_merged(kc, vc, qfA0, qfA1, qfB0, qfB1, mB + c16, sb, wave + 1, true,
                        oA, oB, lA, lB, lane);
        } else if (t < qtA) {
            step_single(kc, vc, qfA0, qfA1, 0, sb, 4, false, oA, lA, lane);
        } else {
            step_single(kc, vc, qfA0, qfA1, mA + c16, sb, wave + 1, true, oA, lA, lane);
        }
        __builtin_amdgcn_s_setprio(0);
    }

    store_frag(lA, oA, Op, mA, c16, quad);
    store_frag(lB, oB, Op, mB, c16, quad);
}

// ---------------------------------------------------------------------------
// Fallback (R2 kernel, proven): used only if ws_size < 32 MB
// ---------------------------------------------------------------------------
__global__ __launch_bounds__(256, 2)
void attn_fwd_fb(const float* __restrict__ Q, const float* __restrict__ K,
                 const float* __restrict__ V, float* __restrict__ O)
{
    constexpr int FSTR = 72;
    constexpr int FQT = 64;
    __shared__ __align__(16) short q_s[FQT * FSTR];
    __shared__ __align__(16) short k_s[64 * FSTR];
    __shared__ __align__(16) short vt_s[E * FSTR];
    __shared__ __align__(16) short p_s[4][16 * FSTR];

    const int tid  = threadIdx.x;
    const int wave = tid >> 6;
    const int lane = tid & 63;
    const int c16  = lane & 15;
    const int quad = lane >> 4;

    const int nqt = L / FQT;
    const int qt  = (nqt - 1) - (int)(blockIdx.x % nqt);
    const int bh  = blockIdx.x / nqt;
    const int b   = bh >> 4;
    const int h   = bh & 15;
    const int q_base = qt * FQT;

    const float* Qp = Q + ((size_t)b * L) * D + h * E;
    const float* Kp = K + ((size_t)b * L) * D + h * E;
    const float* Vp = V + ((size_t)b * L) * D + h * E;
    float*       Op = O + ((size_t)b * L) * D + h * E;

    #pragma unroll
    for (int p = 0; p < 4; ++p) {
        int idx = p * 256 + tid;
        int r = idx >> 4, c4 = (idx & 15) * 4;
        float4 f = *(const float4*)(Qp + (size_t)(q_base + r) * D + c4);
        union { short s[4]; uint2 u; } pk;
        pk.s[0] = bf16_bits(f.x); pk.s[1] = bf16_bits(f.y);
        pk.s[2] = bf16_bits(f.z); pk.s[3] = bf16_bits(f.w);
        *(uint2*)&q_s[r * FSTR + c4] = pk.u;
    }
    __syncthreads();

    short8 qf0 = *(const short8*)&q_s[(wave * 16 + c16) * FSTR + quad * 8];
    short8 qf1 = *(const short8*)&q_s[(wave * 16 + c16) * FSTR + 32 + quad * 8];

    floatx4 o_acc[4];
    #pragma unroll
    for (int nt = 0; nt < 4; ++nt) o_acc[nt] = (floatx4){0.f, 0.f, 0.f, 0.f};
    float m_run[4], l_run[4];
    #pragma unroll
    for (int r = 0; r < 4; ++r) { m_run[r] = -__builtin_inff(); l_run[r] = 0.f; }

    for (int t = 0; t <= qt; ++t) {
        const int k_base = t * 64;
        __syncthreads();
        #pragma unroll
        for (int p = 0; p < 4; ++p) {
            int idx = p * 256 + tid;
            int r = idx >> 4, c4 = (idx & 15) * 4;
            float4 f = *(const float4*)(Kp + (size_t)(k_base + r) * D + c4);
            union { short s[4]; uint2 u; } pk;
            pk.s[0] = bf16_bits(f.x); pk.s[1] = bf16_bits(f.y);
            pk.s[2] = bf16_bits(f.z); pk.s[3] = bf16_bits(f.w);
            *(uint2*)&k_s[r * FSTR + c4] = pk.u;
        }
        #pragma unroll
        for (int p = 0; p < 4; ++p) {
            int s  = lane;
            int dg = p * 4 + wave;
            float4 f = *(const float4*)(Vp + (size_t)(k_base + s) * D + dg * 4);
            vt_s[(dg * 4 + 0) * FSTR + s] = bf16_bits(f.x);
            vt_s[(dg * 4 + 1) * FSTR + s] = bf16_bits(f.y);
            vt_s[(dg * 4 + 2) * FSTR + s] = bf16_bits(f.z);
            vt_s[(dg * 4 + 3) * FSTR + s] = bf16_bits(f.w);
        }
        __syncthreads();

        floatx4 sc[4];
        #pragma unroll
        for (int nt = 0; nt < 4; ++nt) {
            floatx4 acc = (floatx4){0.f, 0.f, 0.f, 0.f};
            short8 b0 = *(const short8*)&k_s[(nt * 16 + c16) * FSTR + quad * 8];
            short8 b1 = *(const short8*)&k_s[(nt * 16 + c16) * FSTR + 32 + quad * 8];
            acc = __builtin_amdgcn_mfma_f32_16x16x32_bf16(qf0, b0, acc, 0, 0, 0);
            acc = __builtin_amdgcn_mfma_f32_16x16x32_bf16(qf1, b1, acc, 0, 0, 0);
            sc[nt] = acc;
        }

        const int q_row0 = q_base + wave * 16 + quad * 4;
        #pragma unroll
        for (int nt = 0; nt < 4; ++nt) {
            const int k_col = k_base + nt * 16 + c16;
            #pragma unroll
            for (int r = 0; r < 4; ++r) {
                float s = sc[nt][r] * SCL_LOG2E;
                sc[nt][r] = (k_col <= q_row0 + r) ? s : -__builtin_inff();
            }
        }

        float alpha[4];
        #pragma unroll
        for (int r = 0; r < 4; ++r) {
            float mx = fmaxf(fmaxf(sc[0][r], sc[1][r]), fmaxf(sc[2][r], sc[3][r]));
            mx = fmaxf(mx, __shfl_xor(mx, 1));
            mx = fmaxf(mx, __shfl_xor(mx, 2));
            mx = fmaxf(mx, __shfl_xor(mx, 4));
            mx = fmaxf(mx, __shfl_xor(mx, 8));
            const float m_new = fmaxf(m_run[r], mx);
            alpha[r] = exp2f(m_run[r] - m_new);
            m_run[r] = m_new;
        }
        float psum[4] = {0.f, 0.f, 0.f, 0.f};
        #pragma unroll
        for (int nt = 0; nt < 4; ++nt) {
            #pragma unroll
            for (int r = 0; r < 4; ++r) {
                float p = exp2f(sc[nt][r] - m_run[r]);
                sc[nt][r] = p;
                psum[r] += p;
            }
        }
        #pragma unroll
        for (int r = 0; r < 4; ++r) {
            float s = psum[r];
            s += __shfl_xor(s, 1);
            s += __shfl_xor(s, 2);
            s += __shfl_xor(s, 4);
            s += __shfl_xor(s, 8);
            l_run[r] = l_run[r] * alpha[r] + s;
            #pragma unroll
            for (int nt = 0; nt < 4; ++nt) o_acc[nt][r] *= alpha[r];
        }

        short* pw = &p_s[wave][0];
        #pragma unroll
        for (int nt = 0; nt < 4; ++nt) {
            #pragma unroll
            for (int r = 0; r < 4; ++r)
                pw[(quad * 4 + r) * FSTR + nt * 16 + c16] = bf16_bits(sc[nt][r]);
        }
        __syncthreads();

        #pragma unroll
        for (int kc = 0; kc < 2; ++kc) {
            short8 pa = *(const short8*)&pw[c16 * FSTR + kc * 32 + quad * 8];
            #pragma unroll
            for (int nt = 0; nt < 4; ++nt) {
                short8 vb = *(const short8*)&vt_s[(nt * 16 + c16) * FSTR + kc * 32 + quad * 8];
                o_acc[nt] = __builtin_amdgcn_mfma_f32_16x16x32_bf16(pa, vb, o_acc[nt], 0, 0, 0);
            }
        }
    }

    const int q_row0 = q_base + wave * 16 + quad * 4;
    #pragma unroll
    for (int r = 0; r < 4; ++r) {
        const float inv_l = 1.f / l_run[r];
        #pragma unroll
        for (int nt = 0; nt < 4; ++nt)
            Op[(size_t)(q_row0 + r) * D + nt * 16 + c16] = o_acc[nt][r] * inv_l;
    }
}

extern "C" void kernel_launch(void* const* d_in, const int* in_sizes, int n_in,
                              void* d_out, int out_size, void* d_ws, size_t ws_size,
                              hipStream_t stream)
{
    const float* Q = (const float*)d_in[0];
    const float* K = (const float*)d_in[1];
    const float* V = (const float*)d_in[2];
    float* O = (float*)d_out;

    const size_t elems = (size_t)B * H * L * E;          // 8M per tensor
    const size_t need  = 2 * elems * sizeof(short);      // 32 MiB

    if (ws_size >= need) {
        short* Kb = (short*)d_ws;
        short* Vt = Kb + elems;
        prep_kv<<<dim3(B * H * 32), dim3(256), 0, stream>>>(K, V, Kb, Vt);
        attn_fwd_p<<<dim3(B * H * 16), dim3(256), 0, stream>>>(Q, Kb, Vt, O);
    } else {
        attn_fwd_fb<<<dim3(B * H * (L / 64)), dim3(256), 0, stream>>>(Q, K, V, O);
    }
}

// Round 4
// 238.036 us; speedup vs baseline: 1.0188x; 1.0188x over previous
//
#include <hip/hip_runtime.h>
#include <hip/hip_bf16.h>

typedef __attribute__((ext_vector_type(8))) short short8;
typedef __attribute__((ext_vector_type(4))) short short4v;
typedef __attribute__((ext_vector_type(4))) float floatx4;

constexpr int B = 4, L = 2048, H = 16, E = 64, D = 1024;
constexpr int STR = 72;   // prep LDS transpose stride (144 B rows, 16B-aligned)
constexpr float SCL_LOG2E = 0.125f * 1.4426950408889634f;  // 1/sqrt(64) * log2(e)

__device__ __forceinline__ short bf16_bits(float x) {
    __hip_bfloat16 b = __float2bfloat16(x);
    return *(const short*)&b;
}

__device__ __forceinline__ short8 packq8(float4 a, float4 c, float scl) {
    short8 r;
    r[0] = bf16_bits(a.x * scl); r[1] = bf16_bits(a.y * scl);
    r[2] = bf16_bits(a.z * scl); r[3] = bf16_bits(a.w * scl);
    r[4] = bf16_bits(c.x * scl); r[5] = bf16_bits(c.y * scl);
    r[6] = bf16_bits(c.z * scl); r[7] = bf16_bits(c.w * scl);
    return r;
}

// Direct global->LDS DMA, 16B/lane. LDS dest = wave-uniform base + lane*16.
__device__ __forceinline__ void load_lds16(const short* g, short* l) {
    __builtin_amdgcn_global_load_lds(
        (const __attribute__((address_space(1))) unsigned int*)g,
        (__attribute__((address_space(3))) unsigned int*)l, 16, 0, 0);
}

// ---------------------------------------------------------------------------
// Prep: emit K and V^T per 64-s tile ALREADY IN MFMA-FRAGMENT ORDER so the
// main kernel's LDS staging and fragment reads are lane-linear (0 conflicts).
//
// K tile (8KB, 512x16B chunks): chunk f = (nt*2+h)*64 + quad*16 + c16
//   holds K[s = nt*16+c16][d = h*32 + quad*8 .. +8)
// V tile (8KB, 1024x8B chunks): chunk g = st*256 + dt*64 + qd*16 + c
//   holds V[s = st*16 + qd*4 .. +4)[d = dt*16 + c]   (i.e. V^T 4-s runs)
// ---------------------------------------------------------------------------
__global__ __launch_bounds__(256)
void prep_kv(const float* __restrict__ K, const float* __restrict__ V,
             short* __restrict__ Kb, short* __restrict__ Vt)
{
    __shared__ __align__(16) short vt[64 * STR];
    const int tid = threadIdx.x;
    const int bh = blockIdx.x >> 5, kt = blockIdx.x & 31;
    const int b = bh >> 4, h = bh & 15;

    const float* Kp = K + ((size_t)(b * L + kt * 64)) * D + h * E;
    const float* Vp = V + ((size_t)(b * L + kt * 64)) * D + h * E;
    short* Kop = Kb + ((size_t)(bh * 32 + kt)) * 4096;
    short* Vop = Vt + ((size_t)(bh * 32 + kt)) * 4096;

    // ---- K: global fp32 -> bf16, fragment-ordered 16B chunks ----
    #pragma unroll
    for (int it = 0; it < 2; ++it) {
        int f = it * 256 + tid;
        int nt = f >> 7, hh = (f >> 6) & 1, qd = (f >> 4) & 3, cc = f & 15;
        int s = nt * 16 + cc, d0 = hh * 32 + qd * 8;
        const float* p = Kp + (size_t)s * D + d0;
        float4 x = *(const float4*)p;
        float4 y = *(const float4*)(p + 4);
        union { short sh[8]; uint4 u; } pk;
        pk.sh[0] = bf16_bits(x.x); pk.sh[1] = bf16_bits(x.y);
        pk.sh[2] = bf16_bits(x.z); pk.sh[3] = bf16_bits(x.w);
        pk.sh[4] = bf16_bits(y.x); pk.sh[5] = bf16_bits(y.y);
        pk.sh[6] = bf16_bits(y.z); pk.sh[7] = bf16_bits(y.w);
        *(uint4*)(Kop + (size_t)f * 8) = pk.u;
    }

    // ---- V phase 1: transpose into LDS vt[d][s] ----
    #pragma unroll
    for (int p = 0; p < 4; ++p) {
        int idx = p * 256 + tid;
        int s = idx >> 4, c4 = (idx & 15) * 4;
        float4 g = *(const float4*)(Vp + (size_t)s * D + c4);
        vt[(c4 + 0) * STR + s] = bf16_bits(g.x);
        vt[(c4 + 1) * STR + s] = bf16_bits(g.y);
        vt[(c4 + 2) * STR + s] = bf16_bits(g.z);
        vt[(c4 + 3) * STR + s] = bf16_bits(g.w);
    }
    __syncthreads();

    // ---- V phase 2: fragment-ordered store (two 8B chunks -> one 16B) ----
    #pragma unroll
    for (int it = 0; it < 2; ++it) {
        int f16 = it * 256 + tid;
        int f8 = f16 * 2;                    // even -> pair shares (st,dt,quad)
        int st = f8 >> 8, dt = (f8 >> 6) & 3, qd = (f8 >> 4) & 3;
        int cA = f8 & 15;                    // even
        int dA = dt * 16 + cA, dB = dA + 1;
        int s0 = st * 16 + qd * 4;
        uint2 a = *(const uint2*)&vt[dA * STR + s0];
        uint2 c = *(const uint2*)&vt[dB * STR + s0];
        uint4 u; u.x = a.x; u.y = a.y; u.z = c.x; u.w = c.y;
        *(uint4*)(Vop + (size_t)f16 * 8) = u;
    }
}

// ---------------------------------------------------------------------------
// Full (interior) step for a 32-row wave: two 16-row fragments (F0 rows m0..,
// F1 rows m0+16..) SHARE every K and V fragment read -> 32 q-rows per 16KB
// LDS tile read, and two independent MFMA chains for ILP.
// ---------------------------------------------------------------------------
__device__ __forceinline__ void step_full(
    const short* __restrict__ kc, const short* __restrict__ vc,
    short8 q00, short8 q01, short8 q10, short8 q11,
    floatx4 (&o0)[4], floatx4 (&o1)[4], float& l0, float& l1, int lane)
{
    short4v p0[4], p1[4];
    #pragma unroll
    for (int nt = 0; nt < 4; ++nt) {
        short8 kb0 = *(const short8*)&kc[nt * 1024 + lane * 8];
        short8 kb1 = *(const short8*)&kc[nt * 1024 + 512 + lane * 8];
        floatx4 a0 = (floatx4){0.f, 0.f, 0.f, 0.f};
        a0 = __builtin_amdgcn_mfma_f32_16x16x32_bf16(kb0, q00, a0, 0, 0, 0);
        a0 = __builtin_amdgcn_mfma_f32_16x16x32_bf16(kb1, q01, a0, 0, 0, 0);
        floatx4 a1 = (floatx4){0.f, 0.f, 0.f, 0.f};
        a1 = __builtin_amdgcn_mfma_f32_16x16x32_bf16(kb0, q10, a1, 0, 0, 0);
        a1 = __builtin_amdgcn_mfma_f32_16x16x32_bf16(kb1, q11, a1, 0, 0, 0);
        #pragma unroll
        for (int r = 0; r < 4; ++r) {
            float pa = __builtin_amdgcn_exp2f(a0[r]);
            float pb = __builtin_amdgcn_exp2f(a1[r]);
            l0 += pa; l1 += pb;
            p0[nt][r] = bf16_bits(pa);
            p1[nt][r] = bf16_bits(pb);
        }
    }
    #pragma unroll
    for (int st = 0; st < 4; ++st) {
        #pragma unroll
        for (int dt = 0; dt < 4; ++dt) {
            short4v vb = *(const short4v*)&vc[(st * 4 + dt) * 256 + lane * 4];
            o0[dt] = __builtin_amdgcn_mfma_f32_16x16x16bf16_1k(p0[st], vb, o0[dt], 0, 0, 0);
            o1[dt] = __builtin_amdgcn_mfma_f32_16x16x16bf16_1k(p1[st], vb, o1[dt], 0, 0, 0);
        }
    }
}

// ---------------------------------------------------------------------------
// Diagonal step: exactly one per wave. cnt0 = active chunks of F0 (1 or 3,
// wave-uniform), F1 has cnt0+1. F0 masks chunk cnt0-1, F1 masks chunk cnt0.
// (m0 is 16-aligned within the 64-wide tile -> single masked chunk per frag.)
// ---------------------------------------------------------------------------
__device__ __forceinline__ void step_diag(
    const short* __restrict__ kc, const short* __restrict__ vc,
    short8 q00, short8 q01, short8 q10, short8 q11,
    int cnt0, int mrow0, int s_base,   // mrow0 = m0+c16 ; s_base = t*64+quad*4
    floatx4 (&o0)[4], floatx4 (&o1)[4], float& l0, float& l1, int lane)
{
    const int cnt1 = cnt0 + 1;
    short4v p0[4], p1[4];
    #pragma unroll
    for (int nt = 0; nt < 4; ++nt) {
        if (nt < cnt1) {
            short8 kb0 = *(const short8*)&kc[nt * 1024 + lane * 8];
            short8 kb1 = *(const short8*)&kc[nt * 1024 + 512 + lane * 8];
            const int s0 = s_base + nt * 16;
            // F1 (upper 16 rows): active on all nt < cnt1, mask at nt == cnt0
            floatx4 a1 = (floatx4){0.f, 0.f, 0.f, 0.f};
            a1 = __builtin_amdgcn_mfma_f32_16x16x32_bf16(kb0, q10, a1, 0, 0, 0);
            a1 = __builtin_amdgcn_mfma_f32_16x16x32_bf16(kb1, q11, a1, 0, 0, 0);
            if (nt == cnt0) {
                #pragma unroll
                for (int r = 0; r < 4; ++r)
                    if (s0 + r > mrow0 + 16) a1[r] = -__builtin_inff();
            }
            #pragma unroll
            for (int r = 0; r < 4; ++r) {
                float pb = __builtin_amdgcn_exp2f(a1[r]);
                l1 += pb;
                p1[nt][r] = bf16_bits(pb);
            }
            // F0 (lower 16 rows): active on nt < cnt0, mask at nt == cnt0-1
            if (nt < cnt0) {
                floatx4 a0 = (floatx4){0.f, 0.f, 0.f, 0.f};
                a0 = __builtin_amdgcn_mfma_f32_16x16x32_bf16(kb0, q00, a0, 0, 0, 0);
                a0 = __builtin_amdgcn_mfma_f32_16x16x32_bf16(kb1, q01, a0, 0, 0, 0);
                if (nt == cnt0 - 1) {
                    #pragma unroll
                    for (int r = 0; r < 4; ++r)
                        if (s0 + r > mrow0) a0[r] = -__builtin_inff();
                }
                #pragma unroll
                for (int r = 0; r < 4; ++r) {
                    float pa = __builtin_amdgcn_exp2f(a0[r]);
                    l0 += pa;
                    p0[nt][r] = bf16_bits(pa);
                }
            }
        }
    }
    #pragma unroll
    for (int st = 0; st < 4; ++st) {
        if (st < cnt1) {
            #pragma unroll
            for (int dt = 0; dt < 4; ++dt) {
                short4v vb = *(const short4v*)&vc[(st * 4 + dt) * 256 + lane * 4];
                o1[dt] = __builtin_amdgcn_mfma_f32_16x16x16bf16_1k(p1[st], vb, o1[dt], 0, 0, 0);
                if (st < cnt0)
                    o0[dt] = __builtin_amdgcn_mfma_f32_16x16x16bf16_1k(p0[st], vb, o0[dt], 0, 0, 0);
            }
        }
    }
}

__device__ __forceinline__ void store_frag(
    float lsum, const floatx4 (&o)[4], float* __restrict__ Op,
    int row_base, int c16, int quad)
{
    lsum += __shfl_xor(lsum, 16);
    lsum += __shfl_xor(lsum, 32);
    const int row0 = row_base + quad * 4;
    #pragma unroll
    for (int r = 0; r < 4; ++r) {
        const float inv = 1.f / __shfl(lsum, quad * 4 + r);  // l lives at lane c16==row
        #pragma unroll
        for (int dt = 0; dt < 4; ++dt)
            Op[(size_t)(row0 + r) * D + dt * 16 + c16] = o[dt][r] * inv;
    }
}

// ---------------------------------------------------------------------------
// Main: 1024 blocks x 256 threads (4 waves). Block = ONE 128-row q-tile;
// wave owns 32 adjacent rows (two 16-row fragments sharing all K/V reads ->
// 2x arithmetic intensity on EVERY tile, uniform staging per block).
// Exactly one diagonal tile per wave with static (cnt0,cnt1).
// Heavy-first dispatch (qt descends with blockIdx) + 4 blocks/CU backfill
// balances the unpaired per-block work; same-head blocks share an XCD.
// ---------------------------------------------------------------------------
__global__ __launch_bounds__(256, 4)
void attn_fwd_p(const float* __restrict__ Q, const short* __restrict__ Kb,
                const short* __restrict__ Vt, float* __restrict__ O)
{
    __shared__ __align__(16) short k_s[2 * 4096];   // 2 x 8KB K tiles
    __shared__ __align__(16) short v_s[2 * 4096];   // 2 x 8KB V tiles

    const int tid  = threadIdx.x;
    const int wave = tid >> 6;          // 0..3
    const int lane = tid & 63;
    const int c16  = lane & 15;
    const int quad = lane >> 4;

    // 1024 blocks = 64 bh x 16 q-tiles; same-head blocks -> same XCD (i&7),
    // qt descends as blockIdx grows -> heavy blocks dispatched first.
    const int i  = (int)blockIdx.x;
    const int bh = ((i >> 7) << 3) | (i & 7);
    const int qt = 15 - ((i >> 3) & 15);
    const int b  = bh >> 4;
    const int h  = bh & 15;

    const float* Qp  = Q  + ((size_t)b * L) * D + h * E;
    const short* Kbp = Kb + ((size_t)bh * 32) * 4096;
    const short* Vtp = Vt + ((size_t)bh * 32) * 4096;
    float*       Op  = O  + ((size_t)b * L) * D + h * E;

    const int n_tiles = 2 * qt + 2;
    const int m0  = qt * 128 + wave * 32;     // F0 first q-row (F1 = +16)
    const int t_d = 2 * qt + (wave >> 1);     // this wave's diagonal tile
    const int cnt0 = (wave & 1) ? 3 : 1;      // F0 active chunks on t_d

    // ---- Q fragments straight from global fp32 (scale*log2e folded) ----
    const float* qr0 = Qp + (size_t)(m0 + c16) * D + quad * 8;
    short8 q00 = packq8(*(const float4*)(qr0),      *(const float4*)(qr0 + 4),  SCL_LOG2E);
    short8 q01 = packq8(*(const float4*)(qr0 + 32), *(const float4*)(qr0 + 36), SCL_LOG2E);
    const float* qr1 = qr0 + (size_t)16 * D;
    short8 q10 = packq8(*(const float4*)(qr1),      *(const float4*)(qr1 + 4),  SCL_LOG2E);
    short8 q11 = packq8(*(const float4*)(qr1 + 32), *(const float4*)(qr1 + 36), SCL_LOG2E);

    // ---- prologue: stage tile 0 into buffer 0 (direct-to-LDS) ----
    #pragma unroll
    for (int it = 0; it < 2; ++it) {
        int c = it * 256 + tid;
        load_lds16(Kbp + (size_t)c * 8, k_s + c * 8);
        load_lds16(Vtp + (size_t)c * 8, v_s + c * 8);
    }

    floatx4 o0[4], o1[4];
    #pragma unroll
    for (int dt = 0; dt < 4; ++dt) {
        o0[dt] = (floatx4){0.f, 0.f, 0.f, 0.f};
        o1[dt] = (floatx4){0.f, 0.f, 0.f, 0.f};
    }
    float l0 = 0.f, l1 = 0.f;

    for (int t = 0; t < n_tiles; ++t) {
        __syncthreads();   // staging of t drained (vmcnt0) + reads of t-1 done
        const short* kc = k_s + (t & 1) * 4096;
        const short* vc = v_s + (t & 1) * 4096;

        if (t + 1 < n_tiles) {  // stage t+1 into the other buffer (in-flight over compute)
            const size_t nb = (size_t)(t + 1) * 4096;
            short* kn = k_s + ((t + 1) & 1) * 4096;
            short* vn = v_s + ((t + 1) & 1) * 4096;
            #pragma unroll
            for (int it = 0; it < 2; ++it) {
                int c = it * 256 + tid;
                load_lds16(Kbp + nb + (size_t)c * 8, kn + c * 8);
                load_lds16(Vtp + nb + (size_t)c * 8, vn + c * 8);
            }
        }

        __builtin_amdgcn_s_setprio(1);
        if (t < t_d) {
            step_full(kc, vc, q00, q01, q10, q11, o0, o1, l0, l1, lane);
        } else if (t == t_d) {
            step_diag(kc, vc, q00, q01, q10, q11, cnt0, m0 + c16,
                      t * 64 + quad * 4, o0, o1, l0, l1, lane);
        }
        __builtin_amdgcn_s_setprio(0);
    }

    store_frag(l0, o0, Op, m0, c16, quad);
    store_frag(l1, o1, Op, m0 + 16, c16, quad);
}

// ---------------------------------------------------------------------------
// Fallback (R2 kernel, proven): used only if ws_size < 32 MB
// ---------------------------------------------------------------------------
__global__ __launch_bounds__(256, 2)
void attn_fwd_fb(const float* __restrict__ Q, const float* __restrict__ K,
                 const float* __restrict__ V, float* __restrict__ O)
{
    constexpr int FSTR = 72;
    constexpr int FQT = 64;
    __shared__ __align__(16) short q_s[FQT * FSTR];
    __shared__ __align__(16) short k_s[64 * FSTR];
    __shared__ __align__(16) short vt_s[E * FSTR];
    __shared__ __align__(16) short p_s[4][16 * FSTR];

    const int tid  = threadIdx.x;
    const int wave = tid >> 6;
    const int lane = tid & 63;
    const int c16  = lane & 15;
    const int quad = lane >> 4;

    const int nqt = L / FQT;
    const int qt  = (nqt - 1) - (int)(blockIdx.x % nqt);
    const int bh  = blockIdx.x / nqt;
    const int b   = bh >> 4;
    const int h   = bh & 15;
    const int q_base = qt * FQT;

    const float* Qp = Q + ((size_t)b * L) * D + h * E;
    const float* Kp = K + ((size_t)b * L) * D + h * E;
    const float* Vp = V + ((size_t)b * L) * D + h * E;
    float*       Op = O + ((size_t)b * L) * D + h * E;

    #pragma unroll
    for (int p = 0; p < 4; ++p) {
        int idx = p * 256 + tid;
        int r = idx >> 4, c4 = (idx & 15) * 4;
        float4 f = *(const float4*)(Qp + (size_t)(q_base + r) * D + c4);
        union { short s[4]; uint2 u; } pk;
        pk.s[0] = bf16_bits(f.x); pk.s[1] = bf16_bits(f.y);
        pk.s[2] = bf16_bits(f.z); pk.s[3] = bf16_bits(f.w);
        *(uint2*)&q_s[r * FSTR + c4] = pk.u;
    }
    __syncthreads();

    short8 qf0 = *(const short8*)&q_s[(wave * 16 + c16) * FSTR + quad * 8];
    short8 qf1 = *(const short8*)&q_s[(wave * 16 + c16) * FSTR + 32 + quad * 8];

    floatx4 o_acc[4];
    #pragma unroll
    for (int nt = 0; nt < 4; ++nt) o_acc[nt] = (floatx4){0.f, 0.f, 0.f, 0.f};
    float m_run[4], l_run[4];
    #pragma unroll
    for (int r = 0; r < 4; ++r) { m_run[r] = -__builtin_inff(); l_run[r] = 0.f; }

    for (int t = 0; t <= qt; ++t) {
        const int k_base = t * 64;
        __syncthreads();
        #pragma unroll
        for (int p = 0; p < 4; ++p) {
            int idx = p * 256 + tid;
            int r = idx >> 4, c4 = (idx & 15) * 4;
            float4 f = *(const float4*)(Kp + (size_t)(k_base + r) * D + c4);
            union { short s[4]; uint2 u; } pk;
            pk.s[0] = bf16_bits(f.x); pk.s[1] = bf16_bits(f.y);
            pk.s[2] = bf16_bits(f.z); pk.s[3] = bf16_bits(f.w);
            *(uint2*)&k_s[r * FSTR + c4] = pk.u;
        }
        #pragma unroll
        for (int p = 0; p < 4; ++p) {
            int s  = lane;
            int dg = p * 4 + wave;
            float4 f = *(const float4*)(Vp + (size_t)(k_base + s) * D + dg * 4);
            vt_s[(dg * 4 + 0) * FSTR + s] = bf16_bits(f.x);
            vt_s[(dg * 4 + 1) * FSTR + s] = bf16_bits(f.y);
            vt_s[(dg * 4 + 2) * FSTR + s] = bf16_bits(f.z);
            vt_s[(dg * 4 + 3) * FSTR + s] = bf16_bits(f.w);
        }
        __syncthreads();

        floatx4 sc[4];
        #pragma unroll
        for (int nt = 0; nt < 4; ++nt) {
            floatx4 acc = (floatx4){0.f, 0.f, 0.f, 0.f};
            short8 b0 = *(const short8*)&k_s[(nt * 16 + c16) * FSTR + quad * 8];
            short8 b1 = *(const short8*)&k_s[(nt * 16 + c16) * FSTR + 32 + quad * 8];
            acc = __builtin_amdgcn_mfma_f32_16x16x32_bf16(qf0, b0, acc, 0, 0, 0);
            acc = __builtin_amdgcn_mfma_f32_16x16x32_bf16(qf1, b1, acc, 0, 0, 0);
            sc[nt] = acc;
        }

        const int q_row0 = q_base + wave * 16 + quad * 4;
        #pragma unroll
        for (int nt = 0; nt < 4; ++nt) {
            const int k_col = k_base + nt * 16 + c16;
            #pragma unroll
            for (int r = 0; r < 4; ++r) {
                float s = sc[nt][r] * SCL_LOG2E;
                sc[nt][r] = (k_col <= q_row0 + r) ? s : -__builtin_inff();
            }
        }

        float alpha[4];
        #pragma unroll
        for (int r = 0; r < 4; ++r) {
            float mx = fmaxf(fmaxf(sc[0][r], sc[1][r]), fmaxf(sc[2][r], sc[3][r]));
            mx = fmaxf(mx, __shfl_xor(mx, 1));
            mx = fmaxf(mx, __shfl_xor(mx, 2));
            mx = fmaxf(mx, __shfl_xor(mx, 4));
            mx = fmaxf(mx, __shfl_xor(mx, 8));
            const float m_new = fmaxf(m_run[r], mx);
            alpha[r] = exp2f(m_run[r] - m_new);
            m_run[r] = m_new;
        }
        float psum[4] = {0.f, 0.f, 0.f, 0.f};
        #pragma unroll
        for (int nt = 0; nt < 4; ++nt) {
            #pragma unroll
            for (int r = 0; r < 4; ++r) {
                float p = exp2f(sc[nt][r] - m_run[r]);
                sc[nt][r] = p;
                psum[r] += p;
            }
        }
        #pragma unroll
        for (int r = 0; r < 4; ++r) {
            float s = psum[r];
            s += __shfl_xor(s, 1);
            s += __shfl_xor(s, 2);
            s += __shfl_xor(s, 4);
            s += __shfl_xor(s, 8);
            l_run[r] = l_run[r] * alpha[r] + s;
            #pragma unroll
            for (int nt = 0; nt < 4; ++nt) o_acc[nt][r] *= alpha[r];
        }

        short* pw = &p_s[wave][0];
        #pragma unroll
        for (int nt = 0; nt < 4; ++nt) {
            #pragma unroll
            for (int r = 0; r < 4; ++r)
                pw[(quad * 4 + r) * FSTR + nt * 16 + c16] = bf16_bits(sc[nt][r]);
        }
        __syncthreads();

        #pragma unroll
        for (int kc = 0; kc < 2; ++kc) {
            short8 pa = *(const short8*)&pw[c16 * FSTR + kc * 32 + quad * 8];
            #pragma unroll
            for (int nt = 0; nt < 4; ++nt) {
                short8 vb = *(const short8*)&vt_s[(nt * 16 + c16) * FSTR + kc * 32 + quad * 8];
                o_acc[nt] = __builtin_amdgcn_mfma_f32_16x16x32_bf16(pa, vb, o_acc[nt], 0, 0, 0);
            }
        }
    }

    const int q_row0 = q_base + wave * 16 + quad * 4;
    #pragma unroll
    for (int r = 0; r < 4; ++r) {
        const float inv_l = 1.f / l_run[r];
        #pragma unroll
        for (int nt = 0; nt < 4; ++nt)
            Op[(size_t)(q_row0 + r) * D + nt * 16 + c16] = o_acc[nt][r] * inv_l;
    }
}

extern "C" void kernel_launch(void* const* d_in, const int* in_sizes, int n_in,
                              void* d_out, int out_size, void* d_ws, size_t ws_size,
                              hipStream_t stream)
{
    const float* Q = (const float*)d_in[0];
    const float* K = (const float*)d_in[1];
    const float* V = (const float*)d_in[2];
    float* O = (float*)d_out;

    const size_t elems = (size_t)B * H * L * E;          // 8M per tensor
    const size_t need  = 2 * elems * sizeof(short);      // 32 MiB

    if (ws_size >= need) {
        short* Kb = (short*)d_ws;
        short* Vt = Kb + elems;
        prep_kv<<<dim3(B * H * 32), dim3(256), 0, stream>>>(K, V, Kb, Vt);
        attn_fwd_p<<<dim3(B * H * 16), dim3(256), 0, stream>>>(Q, Kb, Vt, O);
    } else {
        attn_fwd_fb<<<dim3(B * H * (L / 64)), dim3(256), 0, stream>>>(Q, K, V, O);
    }
}

// Round 5
// 214.488 us; speedup vs baseline: 1.1306x; 1.1098x over previous
//
#include <hip/hip_runtime.h>
#include <hip/hip_bf16.h>

typedef __attribute__((ext_vector_type(8))) short short8;
typedef __attribute__((ext_vector_type(4))) short short4v;
typedef __attribute__((ext_vector_type(4))) float floatx4;

constexpr int B = 4, L = 2048, H = 16, E = 64, D = 1024;
constexpr int STR = 72;   // prep LDS transpose stride (144 B rows, 16B-aligned)
constexpr float SCL_LOG2E = 0.125f * 1.4426950408889634f;  // 1/sqrt(64) * log2(e)

__device__ __forceinline__ short bf16_bits(float x) {
    __hip_bfloat16 b = __float2bfloat16(x);
    return *(const short*)&b;
}

__device__ __forceinline__ short8 packq8(float4 a, float4 c, float scl) {
    short8 r;
    r[0] = bf16_bits(a.x * scl); r[1] = bf16_bits(a.y * scl);
    r[2] = bf16_bits(a.z * scl); r[3] = bf16_bits(a.w * scl);
    r[4] = bf16_bits(c.x * scl); r[5] = bf16_bits(c.y * scl);
    r[6] = bf16_bits(c.z * scl); r[7] = bf16_bits(c.w * scl);
    return r;
}

// Direct global->LDS DMA, 16B/lane. LDS dest = wave-uniform base + lane*16.
__device__ __forceinline__ void load_lds16(const short* g, short* l) {
    __builtin_amdgcn_global_load_lds(
        (const __attribute__((address_space(1))) unsigned int*)g,
        (__attribute__((address_space(3))) unsigned int*)l, 16, 0, 0);
}

// ---------------------------------------------------------------------------
// Prep: emit K and V^T per 64-s tile ALREADY IN MFMA-FRAGMENT ORDER so the
// main kernel's LDS staging and fragment reads are lane-linear (0 conflicts).
//
// K tile (8KB, 512x16B chunks): chunk f = (nt*2+h)*64 + quad*16 + c16
//   holds K[s = nt*16+c16][d = h*32 + quad*8 .. +8)
// V tile (8KB, 1024x8B chunks): chunk g = st*256 + dt*64 + qd*16 + c
//   holds V[s = st*16 + qd*4 .. +4)[d = dt*16 + c]   (i.e. V^T 4-s runs)
// ---------------------------------------------------------------------------
__global__ __launch_bounds__(256)
void prep_kv(const float* __restrict__ K, const float* __restrict__ V,
             short* __restrict__ Kb, short* __restrict__ Vt)
{
    __shared__ __align__(16) short vt[64 * STR];
    const int tid = threadIdx.x;
    const int bh = blockIdx.x >> 5, kt = blockIdx.x & 31;
    const int b = bh >> 4, h = bh & 15;

    const float* Kp = K + ((size_t)(b * L + kt * 64)) * D + h * E;
    const float* Vp = V + ((size_t)(b * L + kt * 64)) * D + h * E;
    short* Kop = Kb + ((size_t)(bh * 32 + kt)) * 4096;
    short* Vop = Vt + ((size_t)(bh * 32 + kt)) * 4096;

    // ---- K: global fp32 -> bf16, fragment-ordered 16B chunks ----
    #pragma unroll
    for (int it = 0; it < 2; ++it) {
        int f = it * 256 + tid;
        int nt = f >> 7, hh = (f >> 6) & 1, qd = (f >> 4) & 3, cc = f & 15;
        int s = nt * 16 + cc, d0 = hh * 32 + qd * 8;
        const float* p = Kp + (size_t)s * D + d0;
        float4 x = *(const float4*)p;
        float4 y = *(const float4*)(p + 4);
        union { short sh[8]; uint4 u; } pk;
        pk.sh[0] = bf16_bits(x.x); pk.sh[1] = bf16_bits(x.y);
        pk.sh[2] = bf16_bits(x.z); pk.sh[3] = bf16_bits(x.w);
        pk.sh[4] = bf16_bits(y.x); pk.sh[5] = bf16_bits(y.y);
        pk.sh[6] = bf16_bits(y.z); pk.sh[7] = bf16_bits(y.w);
        *(uint4*)(Kop + (size_t)f * 8) = pk.u;
    }

    // ---- V phase 1: transpose into LDS vt[d][s] ----
    #pragma unroll
    for (int p = 0; p < 4; ++p) {
        int idx = p * 256 + tid;
        int s = idx >> 4, c4 = (idx & 15) * 4;
        float4 g = *(const float4*)(Vp + (size_t)s * D + c4);
        vt[(c4 + 0) * STR + s] = bf16_bits(g.x);
        vt[(c4 + 1) * STR + s] = bf16_bits(g.y);
        vt[(c4 + 2) * STR + s] = bf16_bits(g.z);
        vt[(c4 + 3) * STR + s] = bf16_bits(g.w);
    }
    __syncthreads();

    // ---- V phase 2: fragment-ordered store (two 8B chunks -> one 16B) ----
    #pragma unroll
    for (int it = 0; it < 2; ++it) {
        int f16 = it * 256 + tid;
        int f8 = f16 * 2;                    // even -> pair shares (st,dt,quad)
        int st = f8 >> 8, dt = (f8 >> 6) & 3, qd = (f8 >> 4) & 3;
        int cA = f8 & 15;                    // even
        int dA = dt * 16 + cA, dB = dA + 1;
        int s0 = st * 16 + qd * 4;
        uint2 a = *(const uint2*)&vt[dA * STR + s0];
        uint2 c = *(const uint2*)&vt[dB * STR + s0];
        uint4 u; u.x = a.x; u.y = a.y; u.z = c.x; u.w = c.y;
        *(uint4*)(Vop + (size_t)f16 * 8) = u;
    }
}

// ---------------------------------------------------------------------------
// Full (interior) step for a 32-row wave: two 16-row fragments (F0 rows m0..,
// F1 rows m0+16..) SHARE every K and V fragment read -> 32 q-rows per 16KB
// LDS tile read, and two independent MFMA chains for ILP.
// ---------------------------------------------------------------------------
__device__ __forceinline__ void step_full(
    const short* __restrict__ kc, const short* __restrict__ vc,
    short8 q00, short8 q01, short8 q10, short8 q11,
    floatx4 (&o0)[4], floatx4 (&o1)[4], float& l0, float& l1, int lane)
{
    short4v p0[4], p1[4];
    #pragma unroll
    for (int nt = 0; nt < 4; ++nt) {
        short8 kb0 = *(const short8*)&kc[nt * 1024 + lane * 8];
        short8 kb1 = *(const short8*)&kc[nt * 1024 + 512 + lane * 8];
        floatx4 a0 = (floatx4){0.f, 0.f, 0.f, 0.f};
        a0 = __builtin_amdgcn_mfma_f32_16x16x32_bf16(kb0, q00, a0, 0, 0, 0);
        a0 = __builtin_amdgcn_mfma_f32_16x16x32_bf16(kb1, q01, a0, 0, 0, 0);
        floatx4 a1 = (floatx4){0.f, 0.f, 0.f, 0.f};
        a1 = __builtin_amdgcn_mfma_f32_16x16x32_bf16(kb0, q10, a1, 0, 0, 0);
        a1 = __builtin_amdgcn_mfma_f32_16x16x32_bf16(kb1, q11, a1, 0, 0, 0);
        #pragma unroll
        for (int r = 0; r < 4; ++r) {
            float pa = __builtin_amdgcn_exp2f(a0[r]);
            float pb = __builtin_amdgcn_exp2f(a1[r]);
            l0 += pa; l1 += pb;
            p0[nt][r] = bf16_bits(pa);
            p1[nt][r] = bf16_bits(pb);
        }
    }
    #pragma unroll
    for (int st = 0; st < 4; ++st) {
        #pragma unroll
        for (int dt = 0; dt < 4; ++dt) {
            short4v vb = *(const short4v*)&vc[(st * 4 + dt) * 256 + lane * 4];
            o0[dt] = __builtin_amdgcn_mfma_f32_16x16x16bf16_1k(p0[st], vb, o0[dt], 0, 0, 0);
            o1[dt] = __builtin_amdgcn_mfma_f32_16x16x16bf16_1k(p1[st], vb, o1[dt], 0, 0, 0);
        }
    }
}

// ---------------------------------------------------------------------------
// Diagonal step: exactly one per wave. cnt0 = active chunks of F0 (1 or 3,
// wave-uniform), F1 has cnt0+1. F0 masks chunk cnt0-1, F1 masks chunk cnt0.
// (m0 is 16-aligned within the 64-wide tile -> single masked chunk per frag.)
// ---------------------------------------------------------------------------
__device__ __forceinline__ void step_diag(
    const short* __restrict__ kc, const short* __restrict__ vc,
    short8 q00, short8 q01, short8 q10, short8 q11,
    int cnt0, int mrow0, int s_base,   // mrow0 = m0+c16 ; s_base = t*64+quad*4
    floatx4 (&o0)[4], floatx4 (&o1)[4], float& l0, float& l1, int lane)
{
    const int cnt1 = cnt0 + 1;
    short4v p0[4], p1[4];
    #pragma unroll
    for (int nt = 0; nt < 4; ++nt) {
        if (nt < cnt1) {
            short8 kb0 = *(const short8*)&kc[nt * 1024 + lane * 8];
            short8 kb1 = *(const short8*)&kc[nt * 1024 + 512 + lane * 8];
            const int s0 = s_base + nt * 16;
            // F1 (upper 16 rows): active on all nt < cnt1, mask at nt == cnt0
            floatx4 a1 = (floatx4){0.f, 0.f, 0.f, 0.f};
            a1 = __builtin_amdgcn_mfma_f32_16x16x32_bf16(kb0, q10, a1, 0, 0, 0);
            a1 = __builtin_amdgcn_mfma_f32_16x16x32_bf16(kb1, q11, a1, 0, 0, 0);
            if (nt == cnt0) {
                #pragma unroll
                for (int r = 0; r < 4; ++r)
                    if (s0 + r > mrow0 + 16) a1[r] = -__builtin_inff();
            }
            #pragma unroll
            for (int r = 0; r < 4; ++r) {
                float pb = __builtin_amdgcn_exp2f(a1[r]);
                l1 += pb;
                p1[nt][r] = bf16_bits(pb);
            }
            // F0 (lower 16 rows): active on nt < cnt0, mask at nt == cnt0-1
            if (nt < cnt0) {
                floatx4 a0 = (floatx4){0.f, 0.f, 0.f, 0.f};
                a0 = __builtin_amdgcn_mfma_f32_16x16x32_bf16(kb0, q00, a0, 0, 0, 0);
                a0 = __builtin_amdgcn_mfma_f32_16x16x32_bf16(kb1, q01, a0, 0, 0, 0);
                if (nt == cnt0 - 1) {
                    #pragma unroll
                    for (int r = 0; r < 4; ++r)
                        if (s0 + r > mrow0) a0[r] = -__builtin_inff();
                }
                #pragma unroll
                for (int r = 0; r < 4; ++r) {
                    float pa = __builtin_amdgcn_exp2f(a0[r]);
                    l0 += pa;
                    p0[nt][r] = bf16_bits(pa);
                }
            }
        }
    }
    #pragma unroll
    for (int st = 0; st < 4; ++st) {
        if (st < cnt1) {
            #pragma unroll
            for (int dt = 0; dt < 4; ++dt) {
                short4v vb = *(const short4v*)&vc[(st * 4 + dt) * 256 + lane * 4];
                o1[dt] = __builtin_amdgcn_mfma_f32_16x16x16bf16_1k(p1[st], vb, o1[dt], 0, 0, 0);
                if (st < cnt0)
                    o0[dt] = __builtin_amdgcn_mfma_f32_16x16x16bf16_1k(p0[st], vb, o0[dt], 0, 0, 0);
            }
        }
    }
}

__device__ __forceinline__ void store_frag(
    float lsum, const floatx4 (&o)[4], float* __restrict__ Op,
    int row_base, int c16, int quad)
{
    lsum += __shfl_xor(lsum, 16);
    lsum += __shfl_xor(lsum, 32);
    const int row0 = row_base + quad * 4;
    #pragma unroll
    for (int r = 0; r < 4; ++r) {
        const float inv = 1.f / __shfl(lsum, quad * 4 + r);  // l lives at lane c16==row
        #pragma unroll
        for (int dt = 0; dt < 4; ++dt)
            Op[(size_t)(row0 + r) * D + dt * 16 + c16] = o[dt][r] * inv;
    }
}

// ---------------------------------------------------------------------------
// Main: 1024 blocks x 256 threads (4 waves). Block = ONE 128-row q-tile;
// wave owns 32 adjacent rows (two 16-row fragments sharing all K/V reads ->
// 2x arithmetic intensity on EVERY tile, uniform staging per block).
// Exactly one diagonal tile per wave with static (cnt0,cnt1).
//
// PER-CU LOAD BALANCE (the R4 bug): HW places blocks {i, i+256, i+512,
// i+768} on one CU (8 XCDs x 32 CUs round-robin). qt must therefore vary
// with bits 8/9 of i, NOT bits 3-6 alone. Mapping: v=(i>>3)&15,
// qt = bit9 ? 15-v : v  ->  each CU hosts qt = {v, v, 15-v, 15-v}:
// exactly 68 tile-steps per CU (uniform), and the two heavy blocks of a
// v=0 CU are CO-RESIDENT, overlapping each other's barrier/staging stalls
// instead of running a solo tail. (bh,qt) remains bijective.
// ---------------------------------------------------------------------------
__global__ __launch_bounds__(256, 4)
void attn_fwd_p(const float* __restrict__ Q, const short* __restrict__ Kb,
                const short* __restrict__ Vt, float* __restrict__ O)
{
    __shared__ __align__(16) short k_s[2 * 4096];   // 2 x 8KB K tiles
    __shared__ __align__(16) short v_s[2 * 4096];   // 2 x 8KB V tiles

    const int tid  = threadIdx.x;
    const int wave = tid >> 6;          // 0..3
    const int lane = tid & 63;
    const int c16  = lane & 15;
    const int quad = lane >> 4;

    const int i  = (int)blockIdx.x;
    const int v  = (i >> 3) & 15;
    const int qt = ((i >> 9) & 1) ? (15 - v) : v;
    const int bh = (((i >> 7) & 7) << 3) | (i & 7);
    const int b  = bh >> 4;
    const int h  = bh & 15;

    const float* Qp  = Q  + ((size_t)b * L) * D + h * E;
    const short* Kbp = Kb + ((size_t)bh * 32) * 4096;
    const short* Vtp = Vt + ((size_t)bh * 32) * 4096;
    float*       Op  = O  + ((size_t)b * L) * D + h * E;

    const int n_tiles = 2 * qt + 2;
    const int m0  = qt * 128 + wave * 32;     // F0 first q-row (F1 = +16)
    const int t_d = 2 * qt + (wave >> 1);     // this wave's diagonal tile
    const int cnt0 = (wave & 1) ? 3 : 1;      // F0 active chunks on t_d

    // ---- Q fragments straight from global fp32 (scale*log2e folded) ----
    const float* qr0 = Qp + (size_t)(m0 + c16) * D + quad * 8;
    short8 q00 = packq8(*(const float4*)(qr0),      *(const float4*)(qr0 + 4),  SCL_LOG2E);
    short8 q01 = packq8(*(const float4*)(qr0 + 32), *(const float4*)(qr0 + 36), SCL_LOG2E);
    const float* qr1 = qr0 + (size_t)16 * D;
    short8 q10 = packq8(*(const float4*)(qr1),      *(const float4*)(qr1 + 4),  SCL_LOG2E);
    short8 q11 = packq8(*(const float4*)(qr1 + 32), *(const float4*)(qr1 + 36), SCL_LOG2E);

    // ---- prologue: stage tile 0 into buffer 0 (direct-to-LDS) ----
    #pragma unroll
    for (int it = 0; it < 2; ++it) {
        int c = it * 256 + tid;
        load_lds16(Kbp + (size_t)c * 8, k_s + c * 8);
        load_lds16(Vtp + (size_t)c * 8, v_s + c * 8);
    }

    floatx4 o0[4], o1[4];
    #pragma unroll
    for (int dt = 0; dt < 4; ++dt) {
        o0[dt] = (floatx4){0.f, 0.f, 0.f, 0.f};
        o1[dt] = (floatx4){0.f, 0.f, 0.f, 0.f};
    }
    float l0 = 0.f, l1 = 0.f;

    for (int t = 0; t < n_tiles; ++t) {
        __syncthreads();   // staging of t drained (vmcnt0) + reads of t-1 done
        const short* kc = k_s + (t & 1) * 4096;
        const short* vc = v_s + (t & 1) * 4096;

        if (t + 1 < n_tiles) {  // stage t+1 into the other buffer (in-flight over compute)
            const size_t nb = (size_t)(t + 1) * 4096;
            short* kn = k_s + ((t + 1) & 1) * 4096;
            short* vn = v_s + ((t + 1) & 1) * 4096;
            #pragma unroll
            for (int it = 0; it < 2; ++it) {
                int c = it * 256 + tid;
                load_lds16(Kbp + nb + (size_t)c * 8, kn + c * 8);
                load_lds16(Vtp + nb + (size_t)c * 8, vn + c * 8);
            }
        }

        __builtin_amdgcn_s_setprio(1);
        if (t < t_d) {
            step_full(kc, vc, q00, q01, q10, q11, o0, o1, l0, l1, lane);
        } else if (t == t_d) {
            step_diag(kc, vc, q00, q01, q10, q11, cnt0, m0 + c16,
                      t * 64 + quad * 4, o0, o1, l0, l1, lane);
        }
        __builtin_amdgcn_s_setprio(0);
    }

    store_frag(l0, o0, Op, m0, c16, quad);
    store_frag(l1, o1, Op, m0 + 16, c16, quad);
}

// ---------------------------------------------------------------------------
// Fallback (R2 kernel, proven): used only if ws_size < 32 MB
// ---------------------------------------------------------------------------
__global__ __launch_bounds__(256, 2)
void attn_fwd_fb(const float* __restrict__ Q, const float* __restrict__ K,
                 const float* __restrict__ V, float* __restrict__ O)
{
    constexpr int FSTR = 72;
    constexpr int FQT = 64;
    __shared__ __align__(16) short q_s[FQT * FSTR];
    __shared__ __align__(16) short k_s[64 * FSTR];
    __shared__ __align__(16) short vt_s[E * FSTR];
    __shared__ __align__(16) short p_s[4][16 * FSTR];

    const int tid  = threadIdx.x;
    const int wave = tid >> 6;
    const int lane = tid & 63;
    const int c16  = lane & 15;
    const int quad = lane >> 4;

    const int nqt = L / FQT;
    const int qt  = (nqt - 1) - (int)(blockIdx.x % nqt);
    const int bh  = blockIdx.x / nqt;
    const int b   = bh >> 4;
    const int h   = bh & 15;
    const int q_base = qt * FQT;

    const float* Qp = Q + ((size_t)b * L) * D + h * E;
    const float* Kp = K + ((size_t)b * L) * D + h * E;
    const float* Vp = V + ((size_t)b * L) * D + h * E;
    float*       Op = O + ((size_t)b * L) * D + h * E;

    #pragma unroll
    for (int p = 0; p < 4; ++p) {
        int idx = p * 256 + tid;
        int r = idx >> 4, c4 = (idx & 15) * 4;
        float4 f = *(const float4*)(Qp + (size_t)(q_base + r) * D + c4);
        union { short s[4]; uint2 u; } pk;
        pk.s[0] = bf16_bits(f.x); pk.s[1] = bf16_bits(f.y);
        pk.s[2] = bf16_bits(f.z); pk.s[3] = bf16_bits(f.w);
        *(uint2*)&q_s[r * FSTR + c4] = pk.u;
    }
    __syncthreads();

    short8 qf0 = *(const short8*)&q_s[(wave * 16 + c16) * FSTR + quad * 8];
    short8 qf1 = *(const short8*)&q_s[(wave * 16 + c16) * FSTR + 32 + quad * 8];

    floatx4 o_acc[4];
    #pragma unroll
    for (int nt = 0; nt < 4; ++nt) o_acc[nt] = (floatx4){0.f, 0.f, 0.f, 0.f};
    float m_run[4], l_run[4];
    #pragma unroll
    for (int r = 0; r < 4; ++r) { m_run[r] = -__builtin_inff(); l_run[r] = 0.f; }

    for (int t = 0; t <= qt; ++t) {
        const int k_base = t * 64;
        __syncthreads();
        #pragma unroll
        for (int p = 0; p < 4; ++p) {
            int idx = p * 256 + tid;
            int r = idx >> 4, c4 = (idx & 15) * 4;
            float4 f = *(const float4*)(Kp + (size_t)(k_base + r) * D + c4);
            union { short s[4]; uint2 u; } pk;
            pk.s[0] = bf16_bits(f.x); pk.s[1] = bf16_bits(f.y);
            pk.s[2] = bf16_bits(f.z); pk.s[3] = bf16_bits(f.w);
            *(uint2*)&k_s[r * FSTR + c4] = pk.u;
        }
        #pragma unroll
        for (int p = 0; p < 4; ++p) {
            int s  = lane;
            int dg = p * 4 + wave;
            float4 f = *(const float4*)(Vp + (size_t)(k_base + s) * D + dg * 4);
            vt_s[(dg * 4 + 0) * FSTR + s] = bf16_bits(f.x);
            vt_s[(dg * 4 + 1) * FSTR + s] = bf16_bits(f.y);
            vt_s[(dg * 4 + 2) * FSTR + s] = bf16_bits(f.z);
            vt_s[(dg * 4 + 3) * FSTR + s] = bf16_bits(f.w);
        }
        __syncthreads();

        floatx4 sc[4];
        #pragma unroll
        for (int nt = 0; nt < 4; ++nt) {
            floatx4 acc = (floatx4){0.f, 0.f, 0.f, 0.f};
            short8 b0 = *(const short8*)&k_s[(nt * 16 + c16) * FSTR + quad * 8];
            short8 b1 = *(const short8*)&k_s[(nt * 16 + c16) * FSTR + 32 + quad * 8];
            acc = __builtin_amdgcn_mfma_f32_16x16x32_bf16(qf0, b0, acc, 0, 0, 0);
            acc = __builtin_amdgcn_mfma_f32_16x16x32_bf16(qf1, b1, acc, 0, 0, 0);
            sc[nt] = acc;
        }

        const int q_row0 = q_base + wave * 16 + quad * 4;
        #pragma unroll
        for (int nt = 0; nt < 4; ++nt) {
            const int k_col = k_base + nt * 16 + c16;
            #pragma unroll
            for (int r = 0; r < 4; ++r) {
                float s = sc[nt][r] * SCL_LOG2E;
                sc[nt][r] = (k_col <= q_row0 + r) ? s : -__builtin_inff();
            }
        }

        float alpha[4];
        #pragma unroll
        for (int r = 0; r < 4; ++r) {
            float mx = fmaxf(fmaxf(sc[0][r], sc[1][r]), fmaxf(sc[2][r], sc[3][r]));
            mx = fmaxf(mx, __shfl_xor(mx, 1));
            mx = fmaxf(mx, __shfl_xor(mx, 2));
            mx = fmaxf(mx, __shfl_xor(mx, 4));
            mx = fmaxf(mx, __shfl_xor(mx, 8));
            const float m_new = fmaxf(m_run[r], mx);
            alpha[r] = exp2f(m_run[r] - m_new);
            m_run[r] = m_new;
        }
        float psum[4] = {0.f, 0.f, 0.f, 0.f};
        #pragma unroll
        for (int nt = 0; nt < 4; ++nt) {
            #pragma unroll
            for (int r = 0; r < 4; ++r) {
                float p = exp2f(sc[nt][r] - m_run[r]);
                sc[nt][r] = p;
                psum[r] += p;
            }
        }
        #pragma unroll
        for (int r = 0; r < 4; ++r) {
            float s = psum[r];
            s += __shfl_xor(s, 1);
            s += __shfl_xor(s, 2);
            s += __shfl_xor(s, 4);
            s += __shfl_xor(s, 8);
            l_run[r] = l_run[r] * alpha[r] + s;
            #pragma unroll
            for (int nt = 0; nt < 4; ++nt) o_acc[nt][r] *= alpha[r];
        }

        short* pw = &p_s[wave][0];
        #pragma unroll
        for (int nt = 0; nt < 4; ++nt) {
            #pragma unroll
            for (int r = 0; r < 4; ++r)
                pw[(quad * 4 + r) * FSTR + nt * 16 + c16] = bf16_bits(sc[nt][r]);
        }
        __syncthreads();

        #pragma unroll
        for (int kc = 0; kc < 2; ++kc) {
            short8 pa = *(const short8*)&pw[c16 * FSTR + kc * 32 + quad * 8];
            #pragma unroll
            for (int nt = 0; nt < 4; ++nt) {
                short8 vb = *(const short8*)&vt_s[(nt * 16 + c16) * FSTR + kc * 32 + quad * 8];
                o_acc[nt] = __builtin_amdgcn_mfma_f32_16x16x32_bf16(pa, vb, o_acc[nt], 0, 0, 0);
            }
        }
    }

    const int q_row0 = q_base + wave * 16 + quad * 4;
    #pragma unroll
    for (int r = 0; r < 4; ++r) {
        const float inv_l = 1.f / l_run[r];
        #pragma unroll
        for (int nt = 0; nt < 4; ++nt)
            Op[(size_t)(q_row0 + r) * D + nt * 16 + c16] = o_acc[nt][r] * inv_l;
    }
}

extern "C" void kernel_launch(void* const* d_in, const int* in_sizes, int n_in,
                              void* d_out, int out_size, void* d_ws, size_t ws_size,
                              hipStream_t stream)
{
    const float* Q = (const float*)d_in[0];
    const float* K = (const float*)d_in[1];
    const float* V = (const float*)d_in[2];
    float* O = (float*)d_out;

    const size_t elems = (size_t)B * H * L * E;          // 8M per tensor
    const size_t need  = 2 * elems * sizeof(short);      // 32 MiB

    if (ws_size >= need) {
        short* Kb = (short*)d_ws;
        short* Vt = Kb + elems;
        prep_kv<<<dim3(B * H * 32), dim3(256), 0, stream>>>(K, V, Kb, Vt);
        attn_fwd_p<<<dim3(B * H * 16), dim3(256), 0, stream>>>(Q, Kb, Vt, O);
    } else {
        attn_fwd_fb<<<dim3(B * H * (L / 64)), dim3(256), 0, stream>>>(Q, K, V, O);
    }
}

// Round 6
// 204.962 us; speedup vs baseline: 1.1832x; 1.0465x over previous
//
#include <hip/hip_runtime.h>
#include <hip/hip_bf16.h>

typedef __attribute__((ext_vector_type(8))) short short8;
typedef __attribute__((ext_vector_type(4))) short short4v;
typedef __attribute__((ext_vector_type(4))) float floatx4;

constexpr int B = 4, L = 2048, H = 16, E = 64, D = 1024;
constexpr int STR = 72;   // prep LDS transpose stride (144 B rows, 16B-aligned)
constexpr float SCL_LOG2E = 0.125f * 1.4426950408889634f;  // 1/sqrt(64) * log2(e)

__device__ __forceinline__ short bf16_bits(float x) {
    __hip_bfloat16 b = __float2bfloat16(x);
    return *(const short*)&b;
}

__device__ __forceinline__ short8 packq8(float4 a, float4 c, float scl) {
    short8 r;
    r[0] = bf16_bits(a.x * scl); r[1] = bf16_bits(a.y * scl);
    r[2] = bf16_bits(a.z * scl); r[3] = bf16_bits(a.w * scl);
    r[4] = bf16_bits(c.x * scl); r[5] = bf16_bits(c.y * scl);
    r[6] = bf16_bits(c.z * scl); r[7] = bf16_bits(c.w * scl);
    return r;
}

// Concatenate two P chunk fragments into one K=32 A-operand.
// Resulting k-order: k=quad*8+j -> s = (j>>2)*16 + quad*4 + (j&3)  (s_map).
// Vt's prep layout uses the SAME s_map, so no cross-lane repack is needed.
__device__ __forceinline__ short8 cat4(short4v a, short4v b) {
    short8 r;
    r[0] = a[0]; r[1] = a[1]; r[2] = a[2]; r[3] = a[3];
    r[4] = b[0]; r[5] = b[1]; r[6] = b[2]; r[7] = b[3];
    return r;
}

// Direct global->LDS DMA, 16B/lane. LDS dest = wave-uniform base + lane*16.
__device__ __forceinline__ void load_lds16(const short* g, short* l) {
    __builtin_amdgcn_global_load_lds(
        (const __attribute__((address_space(1))) unsigned int*)g,
        (__attribute__((address_space(3))) unsigned int*)l, 16, 0, 0);
}

// ---------------------------------------------------------------------------
// Prep: emit K and V^T per 64-s tile ALREADY IN MFMA-FRAGMENT ORDER so the
// main kernel's LDS staging and fragment reads are lane-linear (0 conflicts).
//
// K tile (8KB, 512x16B chunks): chunk f = (nt*2+h)*64 + quad*16 + c16
//   holds K[s = nt*16+c16][d = h*32 + quad*8 .. +8)
// V tile (8KB, 512x16B chunks): B-operand order for K=32 PV MFMA.
//   chunk g = (sp*4+dt)*64 + quad*16 + c16 holds, for j=0..7:
//     V[sp*32 + (j>>2)*16 + quad*4 + (j&3)][dt*16 + c16]
//   (s-permutation matches the P-operand concat order: j>>2 selects the
//    16-chunk, quad*4+(j&3) the slot within it.)
// ---------------------------------------------------------------------------
__global__ __launch_bounds__(256)
void prep_kv(const float* __restrict__ K, const float* __restrict__ V,
             short* __restrict__ Kb, short* __restrict__ Vt)
{
    __shared__ __align__(16) short vt[64 * STR];
    const int tid = threadIdx.x;
    const int bh = blockIdx.x >> 5, kt = blockIdx.x & 31;
    const int b = bh >> 4, h = bh & 15;

    const float* Kp = K + ((size_t)(b * L + kt * 64)) * D + h * E;
    const float* Vp = V + ((size_t)(b * L + kt * 64)) * D + h * E;
    short* Kop = Kb + ((size_t)(bh * 32 + kt)) * 4096;
    short* Vop = Vt + ((size_t)(bh * 32 + kt)) * 4096;

    // ---- K: global fp32 -> bf16, fragment-ordered 16B chunks ----
    #pragma unroll
    for (int it = 0; it < 2; ++it) {
        int f = it * 256 + tid;
        int nt = f >> 7, hh = (f >> 6) & 1, qd = (f >> 4) & 3, cc = f & 15;
        int s = nt * 16 + cc, d0 = hh * 32 + qd * 8;
        const float* p = Kp + (size_t)s * D + d0;
        float4 x = *(const float4*)p;
        float4 y = *(const float4*)(p + 4);
        union { short sh[8]; uint4 u; } pk;
        pk.sh[0] = bf16_bits(x.x); pk.sh[1] = bf16_bits(x.y);
        pk.sh[2] = bf16_bits(x.z); pk.sh[3] = bf16_bits(x.w);
        pk.sh[4] = bf16_bits(y.x); pk.sh[5] = bf16_bits(y.y);
        pk.sh[6] = bf16_bits(y.z); pk.sh[7] = bf16_bits(y.w);
        *(uint4*)(Kop + (size_t)f * 8) = pk.u;
    }

    // ---- V phase 1: transpose into LDS vt[d][s] ----
    #pragma unroll
    for (int p = 0; p < 4; ++p) {
        int idx = p * 256 + tid;
        int s = idx >> 4, c4 = (idx & 15) * 4;
        float4 g = *(const float4*)(Vp + (size_t)s * D + c4);
        vt[(c4 + 0) * STR + s] = bf16_bits(g.x);
        vt[(c4 + 1) * STR + s] = bf16_bits(g.y);
        vt[(c4 + 2) * STR + s] = bf16_bits(g.z);
        vt[(c4 + 3) * STR + s] = bf16_bits(g.w);
    }
    __syncthreads();

    // ---- V phase 2: K=32 B-operand order (two contiguous 4-s runs) ----
    #pragma unroll
    for (int it = 0; it < 2; ++it) {
        int f16 = it * 256 + tid;
        int sp = f16 >> 8, dt = (f16 >> 6) & 3, qd = (f16 >> 4) & 3, cc = f16 & 15;
        int d = dt * 16 + cc;
        int s0 = sp * 32 + qd * 4;
        uint2 lo = *(const uint2*)&vt[d * STR + s0];        // s0 .. s0+3
        uint2 hi = *(const uint2*)&vt[d * STR + s0 + 16];   // s0+16 .. s0+19
        uint4 u; u.x = lo.x; u.y = lo.y; u.z = hi.x; u.w = hi.y;
        *(uint4*)(Vop + (size_t)f16 * 8) = u;
    }
}

// ---------------------------------------------------------------------------
// Full (interior) step for a 32-row wave: two 16-row fragments (F0 rows m0..,
// F1 rows m0+16..) SHARE every K and V fragment read -> 32 q-rows per 16KB
// LDS tile read. PV uses 16x16x32 (K=32 over a chunk pair): 16 MFMA instead
// of 32 half-rate 16x16x16 -> per-step MFMA cycles -33%.
// ---------------------------------------------------------------------------
__device__ __forceinline__ void step_full(
    const short* __restrict__ kc, const short* __restrict__ vc,
    short8 q00, short8 q01, short8 q10, short8 q11,
    floatx4 (&o0)[4], floatx4 (&o1)[4], float& l0, float& l1, int lane)
{
    short4v p0[4], p1[4];
    #pragma unroll
    for (int nt = 0; nt < 4; ++nt) {
        short8 kb0 = *(const short8*)&kc[nt * 1024 + lane * 8];
        short8 kb1 = *(const short8*)&kc[nt * 1024 + 512 + lane * 8];
        floatx4 a0 = (floatx4){0.f, 0.f, 0.f, 0.f};
        a0 = __builtin_amdgcn_mfma_f32_16x16x32_bf16(kb0, q00, a0, 0, 0, 0);
        a0 = __builtin_amdgcn_mfma_f32_16x16x32_bf16(kb1, q01, a0, 0, 0, 0);
        floatx4 a1 = (floatx4){0.f, 0.f, 0.f, 0.f};
        a1 = __builtin_amdgcn_mfma_f32_16x16x32_bf16(kb0, q10, a1, 0, 0, 0);
        a1 = __builtin_amdgcn_mfma_f32_16x16x32_bf16(kb1, q11, a1, 0, 0, 0);
        #pragma unroll
        for (int r = 0; r < 4; ++r) {
            float pa = __builtin_amdgcn_exp2f(a0[r]);
            float pb = __builtin_amdgcn_exp2f(a1[r]);
            l0 += pa; l1 += pb;
            p0[nt][r] = bf16_bits(pa);
            p1[nt][r] = bf16_bits(pb);
        }
    }
    #pragma unroll
    for (int sp = 0; sp < 2; ++sp) {
        short8 pA = cat4(p0[sp * 2], p0[sp * 2 + 1]);
        short8 pB = cat4(p1[sp * 2], p1[sp * 2 + 1]);
        #pragma unroll
        for (int dt = 0; dt < 4; ++dt) {
            short8 vb = *(const short8*)&vc[(sp * 4 + dt) * 512 + lane * 8];
            o0[dt] = __builtin_amdgcn_mfma_f32_16x16x32_bf16(pA, vb, o0[dt], 0, 0, 0);
            o1[dt] = __builtin_amdgcn_mfma_f32_16x16x32_bf16(pB, vb, o1[dt], 0, 0, 0);
        }
    }
}

// ---------------------------------------------------------------------------
// Diagonal step: exactly one per wave. cnt0 = active chunks of F0 (1 or 3,
// wave-uniform), F1 has cnt1 = cnt0+1 (even). F0 masks chunk cnt0-1, F1
// masks chunk cnt0. F0's inactive chunk inside the active sp range is
// ZERO-FILLED (p=0 contributes nothing to O or l), so PV runs K=32 over
// sp < cnt1/2 for both fragments.
// ---------------------------------------------------------------------------
__device__ __forceinline__ void step_diag(
    const short* __restrict__ kc, const short* __restrict__ vc,
    short8 q00, short8 q01, short8 q10, short8 q11,
    int cnt0, int mrow0, int s_base,   // mrow0 = m0+c16 ; s_base = t*64+quad*4
    floatx4 (&o0)[4], floatx4 (&o1)[4], float& l0, float& l1, int lane)
{
    const int cnt1 = cnt0 + 1;         // 2 or 4
    short4v p0[4], p1[4];
    #pragma unroll
    for (int nt = 0; nt < 4; ++nt) {
        if (nt < cnt1) {
            short8 kb0 = *(const short8*)&kc[nt * 1024 + lane * 8];
            short8 kb1 = *(const short8*)&kc[nt * 1024 + 512 + lane * 8];
            const int s0 = s_base + nt * 16;
            // F1 (upper 16 rows): active on all nt < cnt1, mask at nt == cnt0
            floatx4 a1 = (floatx4){0.f, 0.f, 0.f, 0.f};
            a1 = __builtin_amdgcn_mfma_f32_16x16x32_bf16(kb0, q10, a1, 0, 0, 0);
            a1 = __builtin_amdgcn_mfma_f32_16x16x32_bf16(kb1, q11, a1, 0, 0, 0);
            if (nt == cnt0) {
                #pragma unroll
                for (int r = 0; r < 4; ++r)
                    if (s0 + r > mrow0 + 16) a1[r] = -__builtin_inff();
            }
            #pragma unroll
            for (int r = 0; r < 4; ++r) {
                float pb = __builtin_amdgcn_exp2f(a1[r]);
                l1 += pb;
                p1[nt][r] = bf16_bits(pb);
            }
            // F0 (lower 16 rows): active on nt < cnt0, mask at nt == cnt0-1
            if (nt < cnt0) {
                floatx4 a0 = (floatx4){0.f, 0.f, 0.f, 0.f};
                a0 = __builtin_amdgcn_mfma_f32_16x16x32_bf16(kb0, q00, a0, 0, 0, 0);
                a0 = __builtin_amdgcn_mfma_f32_16x16x32_bf16(kb1, q01, a0, 0, 0, 0);
                if (nt == cnt0 - 1) {
                    #pragma unroll
                    for (int r = 0; r < 4; ++r)
                        if (s0 + r > mrow0) a0[r] = -__builtin_inff();
                }
                #pragma unroll
                for (int r = 0; r < 4; ++r) {
                    float pa = __builtin_amdgcn_exp2f(a0[r]);
                    l0 += pa;
                    p0[nt][r] = bf16_bits(pa);
                }
            } else {
                p0[nt] = (short4v){0, 0, 0, 0};   // masked chunk: p = 0
            }
        }
    }
    const int spc = cnt1 >> 1;         // 1 or 2, wave-uniform
    #pragma unroll
    for (int sp = 0; sp < 2; ++sp) {
        if (sp < spc) {
            short8 pA = cat4(p0[sp * 2], p0[sp * 2 + 1]);
            short8 pB = cat4(p1[sp * 2], p1[sp * 2 + 1]);
            #pragma unroll
            for (int dt = 0; dt < 4; ++dt) {
                short8 vb = *(const short8*)&vc[(sp * 4 + dt) * 512 + lane * 8];
                o0[dt] = __builtin_amdgcn_mfma_f32_16x16x32_bf16(pA, vb, o0[dt], 0, 0, 0);
                o1[dt] = __builtin_amdgcn_mfma_f32_16x16x32_bf16(pB, vb, o1[dt], 0, 0, 0);
            }
        }
    }
}

__device__ __forceinline__ void store_frag(
    float lsum, const floatx4 (&o)[4], float* __restrict__ Op,
    int row_base, int c16, int quad)
{
    lsum += __shfl_xor(lsum, 16);
    lsum += __shfl_xor(lsum, 32);
    const int row0 = row_base + quad * 4;
    #pragma unroll
    for (int r = 0; r < 4; ++r) {
        const float inv = 1.f / __shfl(lsum, quad * 4 + r);  // l lives at lane c16==row
        #pragma unroll
        for (int dt = 0; dt < 4; ++dt)
            Op[(size_t)(row0 + r) * D + dt * 16 + c16] = o[dt][r] * inv;
    }
}

// ---------------------------------------------------------------------------
// Main: 1024 blocks x 256 threads (4 waves). Block = ONE 128-row q-tile;
// wave owns 32 adjacent rows (two 16-row fragments sharing all K/V reads ->
// 2x arithmetic intensity on EVERY tile, uniform staging per block).
// Exactly one diagonal tile per wave with static (cnt0,cnt1).
//
// PER-CU LOAD BALANCE: HW places blocks {i, i+256, i+512, i+768} on one CU.
// Mapping: v=(i>>3)&15, qt = bit9 ? 15-v : v  ->  each CU hosts qt =
// {v, v, 15-v, 15-v}: exactly 68 tile-steps per CU (uniform), heavy blocks
// co-resident in pairs. (R4's all-same-qt variant measured WORSE - LDS and
// staging contention - keep this mapping.)
// ---------------------------------------------------------------------------
__global__ __launch_bounds__(256, 4)
void attn_fwd_p(const float* __restrict__ Q, const short* __restrict__ Kb,
                const short* __restrict__ Vt, float* __restrict__ O)
{
    __shared__ __align__(16) short k_s[2 * 4096];   // 2 x 8KB K tiles
    __shared__ __align__(16) short v_s[2 * 4096];   // 2 x 8KB V tiles

    const int tid  = threadIdx.x;
    const int wave = tid >> 6;          // 0..3
    const int lane = tid & 63;
    const int c16  = lane & 15;
    const int quad = lane >> 4;

    const int i  = (int)blockIdx.x;
    const int v  = (i >> 3) & 15;
    const int qt = ((i >> 9) & 1) ? (15 - v) : v;
    const int bh = (((i >> 7) & 7) << 3) | (i & 7);
    const int b  = bh >> 4;
    const int h  = bh & 15;

    const float* Qp  = Q  + ((size_t)b * L) * D + h * E;
    const short* Kbp = Kb + ((size_t)bh * 32) * 4096;
    const short* Vtp = Vt + ((size_t)bh * 32) * 4096;
    float*       Op  = O  + ((size_t)b * L) * D + h * E;

    const int n_tiles = 2 * qt + 2;
    const int m0  = qt * 128 + wave * 32;     // F0 first q-row (F1 = +16)
    const int t_d = 2 * qt + (wave >> 1);     // this wave's diagonal tile
    const int cnt0 = (wave & 1) ? 3 : 1;      // F0 active chunks on t_d

    // ---- Q fragments straight from global fp32 (scale*log2e folded) ----
    const float* qr0 = Qp + (size_t)(m0 + c16) * D + quad * 8;
    short8 q00 = packq8(*(const float4*)(qr0),      *(const float4*)(qr0 + 4),  SCL_LOG2E);
    short8 q01 = packq8(*(const float4*)(qr0 + 32), *(const float4*)(qr0 + 36), SCL_LOG2E);
    const float* qr1 = qr0 + (size_t)16 * D;
    short8 q10 = packq8(*(const float4*)(qr1),      *(const float4*)(qr1 + 4),  SCL_LOG2E);
    short8 q11 = packq8(*(const float4*)(qr1 + 32), *(const float4*)(qr1 + 36), SCL_LOG2E);

    // ---- prologue: stage tile 0 into buffer 0 (direct-to-LDS) ----
    #pragma unroll
    for (int it = 0; it < 2; ++it) {
        int c = it * 256 + tid;
        load_lds16(Kbp + (size_t)c * 8, k_s + c * 8);
        load_lds16(Vtp + (size_t)c * 8, v_s + c * 8);
    }

    floatx4 o0[4], o1[4];
    #pragma unroll
    for (int dt = 0; dt < 4; ++dt) {
        o0[dt] = (floatx4){0.f, 0.f, 0.f, 0.f};
        o1[dt] = (floatx4){0.f, 0.f, 0.f, 0.f};
    }
    float l0 = 0.f, l1 = 0.f;

    for (int t = 0; t < n_tiles; ++t) {
        __syncthreads();   // staging of t drained (vmcnt0) + reads of t-1 done
        const short* kc = k_s + (t & 1) * 4096;
        const short* vc = v_s + (t & 1) * 4096;

        if (t + 1 < n_tiles) {  // stage t+1 into the other buffer (in-flight over compute)
            const size_t nb = (size_t)(t + 1) * 4096;
            short* kn = k_s + ((t + 1) & 1) * 4096;
            short* vn = v_s + ((t + 1) & 1) * 4096;
            #pragma unroll
            for (int it = 0; it < 2; ++it) {
                int c = it * 256 + tid;
                load_lds16(Kbp + nb + (size_t)c * 8, kn + c * 8);
                load_lds16(Vtp + nb + (size_t)c * 8, vn + c * 8);
            }
        }

        __builtin_amdgcn_s_setprio(1);
        if (t < t_d) {
            step_full(kc, vc, q00, q01, q10, q11, o0, o1, l0, l1, lane);
        } else if (t == t_d) {
            step_diag(kc, vc, q00, q01, q10, q11, cnt0, m0 + c16,
                      t * 64 + quad * 4, o0, o1, l0, l1, lane);
        }
        __builtin_amdgcn_s_setprio(0);
    }

    store_frag(l0, o0, Op, m0, c16, quad);
    store_frag(l1, o1, Op, m0 + 16, c16, quad);
}

// ---------------------------------------------------------------------------
// Fallback (R2 kernel, proven): used only if ws_size < 32 MB
// ---------------------------------------------------------------------------
__global__ __launch_bounds__(256, 2)
void attn_fwd_fb(const float* __restrict__ Q, const float* __restrict__ K,
                 const float* __restrict__ V, float* __restrict__ O)
{
    constexpr int FSTR = 72;
    constexpr int FQT = 64;
    __shared__ __align__(16) short q_s[FQT * FSTR];
    __shared__ __align__(16) short k_s[64 * FSTR];
    __shared__ __align__(16) short vt_s[E * FSTR];
    __shared__ __align__(16) short p_s[4][16 * FSTR];

    const int tid  = threadIdx.x;
    const int wave = tid >> 6;
    const int lane = tid & 63;
    const int c16  = lane & 15;
    const int quad = lane >> 4;

    const int nqt = L / FQT;
    const int qt  = (nqt - 1) - (int)(blockIdx.x % nqt);
    const int bh  = blockIdx.x / nqt;
    const int b   = bh >> 4;
    const int h   = bh & 15;
    const int q_base = qt * FQT;

    const float* Qp = Q + ((size_t)b * L) * D + h * E;
    const float* Kp = K + ((size_t)b * L) * D + h * E;
    const float* Vp = V + ((size_t)b * L) * D + h * E;
    float*       Op = O + ((size_t)b * L) * D + h * E;

    #pragma unroll
    for (int p = 0; p < 4; ++p) {
        int idx = p * 256 + tid;
        int r = idx >> 4, c4 = (idx & 15) * 4;
        float4 f = *(const float4*)(Qp + (size_t)(q_base + r) * D + c4);
        union { short s[4]; uint2 u; } pk;
        pk.s[0] = bf16_bits(f.x); pk.s[1] = bf16_bits(f.y);
        pk.s[2] = bf16_bits(f.z); pk.s[3] = bf16_bits(f.w);
        *(uint2*)&q_s[r * FSTR + c4] = pk.u;
    }
    __syncthreads();

    short8 qf0 = *(const short8*)&q_s[(wave * 16 + c16) * FSTR + quad * 8];
    short8 qf1 = *(const short8*)&q_s[(wave * 16 + c16) * FSTR + 32 + quad * 8];

    floatx4 o_acc[4];
    #pragma unroll
    for (int nt = 0; nt < 4; ++nt) o_acc[nt] = (floatx4){0.f, 0.f, 0.f, 0.f};
    float m_run[4], l_run[4];
    #pragma unroll
    for (int r = 0; r < 4; ++r) { m_run[r] = -__builtin_inff(); l_run[r] = 0.f; }

    for (int t = 0; t <= qt; ++t) {
        const int k_base = t * 64;
        __syncthreads();
        #pragma unroll
        for (int p = 0; p < 4; ++p) {
            int idx = p * 256 + tid;
            int r = idx >> 4, c4 = (idx & 15) * 4;
            float4 f = *(const float4*)(Kp + (size_t)(k_base + r) * D + c4);
            union { short s[4]; uint2 u; } pk;
            pk.s[0] = bf16_bits(f.x); pk.s[1] = bf16_bits(f.y);
            pk.s[2] = bf16_bits(f.z); pk.s[3] = bf16_bits(f.w);
            *(uint2*)&k_s[r * FSTR + c4] = pk.u;
        }
        #pragma unroll
        for (int p = 0; p < 4; ++p) {
            int s  = lane;
            int dg = p * 4 + wave;
            float4 f = *(const float4*)(Vp + (size_t)(k_base + s) * D + dg * 4);
            vt_s[(dg * 4 + 0) * FSTR + s] = bf16_bits(f.x);
            vt_s[(dg * 4 + 1) * FSTR + s] = bf16_bits(f.y);
            vt_s[(dg * 4 + 2) * FSTR + s] = bf16_bits(f.z);
            vt_s[(dg * 4 + 3) * FSTR + s] = bf16_bits(f.w);
        }
        __syncthreads();

        floatx4 sc[4];
        #pragma unroll
        for (int nt = 0; nt < 4; ++nt) {
            floatx4 acc = (floatx4){0.f, 0.f, 0.f, 0.f};
            short8 b0 = *(const short8*)&k_s[(nt * 16 + c16) * FSTR + quad * 8];
            short8 b1 = *(const short8*)&k_s[(nt * 16 + c16) * FSTR + 32 + quad * 8];
            acc = __builtin_amdgcn_mfma_f32_16x16x32_bf16(qf0, b0, acc, 0, 0, 0);
            acc = __builtin_amdgcn_mfma_f32_16x16x32_bf16(qf1, b1, acc, 0, 0, 0);
            sc[nt] = acc;
        }

        const int q_row0 = q_base + wave * 16 + quad * 4;
        #pragma unroll
        for (int nt = 0; nt < 4; ++nt) {
            const int k_col = k_base + nt * 16 + c16;
            #pragma unroll
            for (int r = 0; r < 4; ++r) {
                float s = sc[nt][r] * SCL_LOG2E;
                sc[nt][r] = (k_col <= q_row0 + r) ? s : -__builtin_inff();
            }
        }

        float alpha[4];
        #pragma unroll
        for (int r = 0; r < 4; ++r) {
            float mx = fmaxf(fmaxf(sc[0][r], sc[1][r]), fmaxf(sc[2][r], sc[3][r]));
            mx = fmaxf(mx, __shfl_xor(mx, 1));
            mx = fmaxf(mx, __shfl_xor(mx, 2));
            mx = fmaxf(mx, __shfl_xor(mx, 4));
            mx = fmaxf(mx, __shfl_xor(mx, 8));
            const float m_new = fmaxf(m_run[r], mx);
            alpha[r] = exp2f(m_run[r] - m_new);
            m_run[r] = m_new;
        }
        float psum[4] = {0.f, 0.f, 0.f, 0.f};
        #pragma unroll
        for (int nt = 0; nt < 4; ++nt) {
            #pragma unroll
            for (int r = 0; r < 4; ++r) {
                float p = exp2f(sc[nt][r] - m_run[r]);
                sc[nt][r] = p;
                psum[r] += p;
            }
        }
        #pragma unroll
        for (int r = 0; r < 4; ++r) {
            float s = psum[r];
            s += __shfl_xor(s, 1);
            s += __shfl_xor(s, 2);
            s += __shfl_xor(s, 4);
            s += __shfl_xor(s, 8);
            l_run[r] = l_run[r] * alpha[r] + s;
            #pragma unroll
            for (int nt = 0; nt < 4; ++nt) o_acc[nt][r] *= alpha[r];
        }

        short* pw = &p_s[wave][0];
        #pragma unroll
        for (int nt = 0; nt < 4; ++nt) {
            #pragma unroll
            for (int r = 0; r < 4; ++r)
                pw[(quad * 4 + r) * FSTR + nt * 16 + c16] = bf16_bits(sc[nt][r]);
        }
        __syncthreads();

        #pragma unroll
        for (int kc = 0; kc < 2; ++kc) {
            short8 pa = *(const short8*)&pw[c16 * FSTR + kc * 32 + quad * 8];
            #pragma unroll
            for (int nt = 0; nt < 4; ++nt) {
                short8 vb = *(const short8*)&vt_s[(nt * 16 + c16) * FSTR + kc * 32 + quad * 8];
                o_acc[nt] = __builtin_amdgcn_mfma_f32_16x16x32_bf16(pa, vb, o_acc[nt], 0, 0, 0);
            }
        }
    }

    const int q_row0 = q_base + wave * 16 + quad * 4;
    #pragma unroll
    for (int r = 0; r < 4; ++r) {
        const float inv_l = 1.f / l_run[r];
        #pragma unroll
        for (int nt = 0; nt < 4; ++nt)
            Op[(size_t)(q_row0 + r) * D + nt * 16 + c16] = o_acc[nt][r] * inv_l;
    }
}

extern "C" void kernel_launch(void* const* d_in, const int* in_sizes, int n_in,
                              void* d_out, int out_size, void* d_ws, size_t ws_size,
                              hipStream_t stream)
{
    const float* Q = (const float*)d_in[0];
    const float* K = (const float*)d_in[1];
    const float* V = (const float*)d_in[2];
    float* O = (float*)d_out;

    const size_t elems = (size_t)B * H * L * E;          // 8M per tensor
    const size_t need  = 2 * elems * sizeof(short);      // 32 MiB

    if (ws_size >= need) {
        short* Kb = (short*)d_ws;
        short* Vt = Kb + elems;
        prep_kv<<<dim3(B * H * 32), dim3(256), 0, stream>>>(K, V, Kb, Vt);
        attn_fwd_p<<<dim3(B * H * 16), dim3(256), 0, stream>>>(Q, Kb, Vt, O);
    } else {
        attn_fwd_fb<<<dim3(B * H * (L / 64)), dim3(256), 0, stream>>>(Q, K, V, O);
    }
}